// Round 4
// baseline (490.384 us; speedup 1.0000x reference)
//
#include <hip/hip_runtime.h>

#define N_NODES 100000
#define N_EDGES 800000
#define D 128

// grid split for the fused front kernel
#define G_MLP 1563            // (N_NODES+63)/64
#define G_DEG 3125            // (N_EDGES+255)/256
#define G_PRE 192             // 384*128/256

typedef __attribute__((ext_vector_type(8))) short short8;
typedef __attribute__((ext_vector_type(4))) float f32x4;

__device__ inline unsigned short f2bf(float f) {
  unsigned u = __float_as_uint(f);
  unsigned r = (u + 0x7fffu + ((u >> 16) & 1u)) >> 16;
  return (unsigned short)r;
}
__device__ inline void bfma8(float* acc, const uint4 v, float d) {
  acc[0] = fmaf(__uint_as_float(v.x << 16), d, acc[0]);
  acc[1] = fmaf(__uint_as_float(v.x & 0xffff0000u), d, acc[1]);
  acc[2] = fmaf(__uint_as_float(v.y << 16), d, acc[2]);
  acc[3] = fmaf(__uint_as_float(v.y & 0xffff0000u), d, acc[3]);
  acc[4] = fmaf(__uint_as_float(v.z << 16), d, acc[4]);
  acc[5] = fmaf(__uint_as_float(v.z & 0xffff0000u), d, acc[5]);
  acc[6] = fmaf(__uint_as_float(v.w << 16), d, acc[6]);
  acc[7] = fmaf(__uint_as_float(v.w & 0xffff0000u), d, acc[7]);
}
__device__ inline void unpack8(float* o, const uint4 v) {
  o[0] = __uint_as_float(v.x << 16); o[1] = __uint_as_float(v.x & 0xffff0000u);
  o[2] = __uint_as_float(v.y << 16); o[3] = __uint_as_float(v.y & 0xffff0000u);
  o[4] = __uint_as_float(v.z << 16); o[5] = __uint_as_float(v.z & 0xffff0000u);
  o[6] = __uint_as_float(v.w << 16); o[7] = __uint_as_float(v.w & 0xffff0000u);
}
__device__ inline uint4 pack8(const float* v) {
  uint4 r;
  r.x = (unsigned)f2bf(v[0]) | ((unsigned)f2bf(v[1]) << 16);
  r.y = (unsigned)f2bf(v[2]) | ((unsigned)f2bf(v[3]) << 16);
  r.z = (unsigned)f2bf(v[4]) | ((unsigned)f2bf(v[5]) << 16);
  r.w = (unsigned)f2bf(v[6]) | ((unsigned)f2bf(v[7]) << 16);
  return r;
}

// ---------------- fused front: MLP (blocks 0..G_MLP) + degree count + wbt ----
// LDS ~25.6 KB (x staged per 32-K pass, like w1) -> 6 blocks/CU.
__global__ __launch_bounds__(256, 4)
void k_front(const float* __restrict__ x, const float* __restrict__ w1,
             const float* __restrict__ w2, const float* __restrict__ b1,
             const float* __restrict__ b2, const float* __restrict__ emb,
             const float* __restrict__ alpha_p, unsigned short* __restrict__ xk_bf,
             const int* __restrict__ dst, int* __restrict__ degs,
             const float* __restrict__ weights, const float* __restrict__ lin_w,
             unsigned short* __restrict__ wbt) {
  int tid = threadIdx.x;
  int bid = blockIdx.x;

  if (bid >= G_MLP) {
    if (bid < G_MLP + G_DEG) {
      // ---- degree count ----
      int e = (bid - G_MLP) * 256 + tid;
      if (e < N_EDGES) atomicAdd(&degs[dst[e]], 1);
    } else {
      // ---- precompute merged weights -> bf16, transposed, stride 392 ----
      int gid = (bid - G_MLP - G_DEG) * 256 + tid;   // 384*128 threads
      int k = gid >> 7, d = gid & 127;
      float v;
      if (k < 128) {
        v = lin_w[d * 256 + k];
      } else {
        const float* wrow = weights + (k - 128) * 128;
        const float* lcol = lin_w + d * 256 + 128;
        float s = 0.f;
        for (int j = 0; j < 128; j++) s += wrow[j] * lcol[j];
        v = s;
      }
      wbt[d * 392 + k] = f2bf(v);
    }
    return;
  }

  // ---- per-node MLP -> prob -> xk(bf16) ----
  __shared__ __align__(16) float xsT[32 * 68];     // per-pass 32-K slice
  __shared__ __align__(16) float w1sT[32 * 128];
  __shared__ float zbuf[64];
  __shared__ float pbuf[64];

  int lane = tid & 63;
  int wave = tid >> 6;
  int n0 = bid * 64;

  int d8 = tid & 15;
  int n4 = tid >> 4;
  float acc[4][8];
  #pragma unroll
  for (int a = 0; a < 4; a++)
    #pragma unroll
    for (int c = 0; c < 8; c++) acc[a][c] = 0.f;

  for (int p = 0; p < 4; p++) {
    __syncthreads();
    {  // stage w1 K-slice, transposed: w1sT[k][j]
      int j = tid >> 1;
      int kg0 = (tid & 1) * 4;
      const float4* wr = (const float4*)(w1 + j * 128 + p * 32);
      #pragma unroll
      for (int c = 0; c < 4; c++) {
        float4 v = wr[kg0 + c];
        int k = (kg0 + c) * 4;
        w1sT[(k + 0) * 128 + j] = v.x;
        w1sT[(k + 1) * 128 + j] = v.y;
        w1sT[(k + 2) * 128 + j] = v.z;
        w1sT[(k + 3) * 128 + j] = v.w;
      }
    }
    {  // stage x K-slice, transposed: xsT[k][n] for k in [0,32)
      int n = lane;
      int gn = n0 + n;
      int k8 = wave * 8;
      const float4* xr = (const float4*)(x + (size_t)gn * 128 + p * 32 + k8);
      float4 v0 = make_float4(0.f, 0.f, 0.f, 0.f), v1 = v0;
      if (gn < N_NODES) { v0 = xr[0]; v1 = xr[1]; }
      xsT[(k8 + 0) * 68 + n] = v0.x;
      xsT[(k8 + 1) * 68 + n] = v0.y;
      xsT[(k8 + 2) * 68 + n] = v0.z;
      xsT[(k8 + 3) * 68 + n] = v0.w;
      xsT[(k8 + 4) * 68 + n] = v1.x;
      xsT[(k8 + 5) * 68 + n] = v1.y;
      xsT[(k8 + 6) * 68 + n] = v1.z;
      xsT[(k8 + 7) * 68 + n] = v1.w;
    }
    __syncthreads();

    for (int kk = 0; kk < 32; kk += 4) {
      float wq[4][8];
      float4 f[4];
      #pragma unroll
      for (int q = 0; q < 4; q++) {
        const float4* wr = (const float4*)(w1sT + (kk + q) * 128 + d8 * 8);
        float4 a = wr[0], b = wr[1];
        wq[q][0] = a.x; wq[q][1] = a.y; wq[q][2] = a.z; wq[q][3] = a.w;
        wq[q][4] = b.x; wq[q][5] = b.y; wq[q][6] = b.z; wq[q][7] = b.w;
        f[q] = *(const float4*)(xsT + (kk + q) * 68 + n4 * 4);
      }
      #pragma unroll
      for (int q = 0; q < 4; q++) {
        #pragma unroll
        for (int c = 0; c < 8; c++) {
          acc[0][c] += f[q].x * wq[q][c];
          acc[1][c] += f[q].y * wq[q][c];
          acc[2][c] += f[q].z * wq[q][c];
          acc[3][c] += f[q].w * wq[q][c];
        }
      }
    }
  }

  {
    int j0 = d8 * 8;
    float bb[8], wd[8];
    #pragma unroll
    for (int c = 0; c < 8; c++) {
      bb[c] = b1[j0 + c];
      wd[c] = w2[128 + j0 + c] - w2[j0 + c];
    }
    #pragma unroll
    for (int a = 0; a < 4; a++) {
      float s = 0.f;
      #pragma unroll
      for (int c = 0; c < 8; c++) {
        float h = fmaxf(acc[a][c] + bb[c], 0.f);
        s += h * wd[c];
      }
      s += __shfl_down(s, 8);
      s += __shfl_down(s, 4);
      s += __shfl_down(s, 2);
      s += __shfl_down(s, 1);
      if (d8 == 0) zbuf[n4 * 4 + a] = s;
    }
  }
  __syncthreads();
  if (tid < 64) {
    float db2 = b2[1] - b2[0];
    float z = zbuf[tid] + db2;
    pbuf[tid] = 1.f / (1.f + expf(-z));
  }
  __syncthreads();

  {
    float al = alpha_p[0];
    int d4 = tid & 31;
    const float4 e0 = ((const float4*)emb)[d4];
    const float4 e1 = ((const float4*)(emb + 128))[d4];
    #pragma unroll
    for (int i = 0; i < 8; i++) {
      int n = i * 8 + (tid >> 5);
      int gn = n0 + n;
      if (gn >= N_NODES) continue;
      float p = pbuf[n];
      float c0 = al * (1.f - p), c1 = al * p;
      float4 xv = ((const float4*)x)[(size_t)gn * 32 + d4];
      float o0 = xv.x + c0 * e0.x + c1 * e1.x;
      float o1 = xv.y + c0 * e0.y + c1 * e1.y;
      float o2 = xv.z + c0 * e0.z + c1 * e1.z;
      float o3 = xv.w + c0 * e0.w + c1 * e1.w;
      ushort4 ov = make_ushort4(f2bf(o0), f2bf(o1), f2bf(o2), f2bf(o3));
      ((ushort4*)xk_bf)[(size_t)gn * 32 + d4] = ov;
    }
  }
}

// ---------------- 2-level exclusive scan over degrees ----------------
__global__ void k_scan1(const int* __restrict__ degs, int* __restrict__ offs,
                        int* __restrict__ aux) {
  __shared__ int s[256];
  int tid = threadIdx.x;
  int i = blockIdx.x * 256 + tid;
  int v = (i < N_NODES) ? degs[i] : 0;
  int sum = v;
  s[tid] = sum; __syncthreads();
  for (int off = 1; off < 256; off <<= 1) {
    int t = (tid >= off) ? s[tid - off] : 0;
    __syncthreads();
    sum += t; s[tid] = sum;
    __syncthreads();
  }
  if (i < N_NODES) offs[i] = sum - v;
  if (tid == 255) aux[blockIdx.x] = sum;
}

__global__ void k_scan2(const int* __restrict__ aux, int* __restrict__ aux2, int nblk) {
  __shared__ int s[512];
  int tid = threadIdx.x;
  int v = (tid < nblk) ? aux[tid] : 0;
  int sum = v;
  s[tid] = sum; __syncthreads();
  for (int off = 1; off < 512; off <<= 1) {
    int t = (tid >= off) ? s[tid - off] : 0;
    __syncthreads();
    sum += t; s[tid] = sum;
    __syncthreads();
  }
  aux2[tid] = sum - v;
}

__global__ void k_scan3(int* __restrict__ offs, const int* __restrict__ aux2,
                        const int* __restrict__ degs, float* __restrict__ dinv) {
  int i = blockIdx.x * 256 + threadIdx.x;
  if (i < N_NODES) {
    offs[i] += aux2[blockIdx.x];
    dinv[i] = rsqrtf(fmaxf((float)degs[i], 1.0f));
  }
}

// ---------------- CSR fill (counting sort by dst) ----------------
__global__ void k_fill(const int* __restrict__ src, const int* __restrict__ dst,
                       const int* __restrict__ offs, int* __restrict__ cursor,
                       int* __restrict__ csr) {
  int e = blockIdx.x * 256 + threadIdx.x;
  if (e < N_EDGES) {
    int d = dst[e];
    int pos = offs[d] + atomicAdd(&cursor[d], 1);
    csr[pos] = src[e];
  }
}

// ---------------- Laplacian gather passes, bf16 feat, 4 edges/instr ----------
template <int PASS>
__global__ __launch_bounds__(256)
void k_gather(const unsigned short* __restrict__ feat,
              unsigned short* __restrict__ feat_out,
              float* __restrict__ hi,
              unsigned short* __restrict__ ahi,
              const int* __restrict__ csr, const int* __restrict__ offs,
              const int* __restrict__ degs, const float* __restrict__ dinv) {
  int node = blockIdx.x * 4 + (threadIdx.x >> 6);
  int lane = threadIdx.x & 63;
  int quad = lane >> 4;
  int l16 = lane & 15;
  int start = offs[node];
  int cnt = degs[node];
  const uint4* f16 = (const uint4*)feat;   // one row = 16 uint4
  float acc[8];
  #pragma unroll
  for (int i = 0; i < 8; i++) acc[i] = 0.f;

  int j = 0;
  for (; j + 8 <= cnt; j += 8) {            // 8 edges in flight
    int sa = csr[start + j + quad];
    int sb = csr[start + j + 4 + quad];
    float da = dinv[sa], db = dinv[sb];
    uint4 va = f16[(size_t)sa * 16 + l16];
    uint4 vb = f16[(size_t)sb * 16 + l16];
    bfma8(acc, va, da);
    bfma8(acc, vb, db);
  }
  if (j + 4 <= cnt) {
    int s = csr[start + j + quad];
    float d = dinv[s];
    uint4 v = f16[(size_t)s * 16 + l16];
    bfma8(acc, v, d);
    j += 4;
  }
  int rem = cnt - j;                        // 0..3
  if (quad < rem) {
    int s = csr[start + j + quad];
    float d = dinv[s];
    uint4 v = f16[(size_t)s * 16 + l16];
    bfma8(acc, v, d);
  }

  #pragma unroll
  for (int i = 0; i < 8; i++) {
    acc[i] += __shfl_down(acc[i], 32);
    acc[i] += __shfl_down(acc[i], 16);
  }

  if (quad == 0) {
    float dvi = dinv[node];
    float old[8], nw[8];
    unpack8(old, f16[(size_t)node * 16 + l16]);
    #pragma unroll
    for (int i = 0; i < 8; i++) nw[i] = old[i] - acc[i] * dvi;
    if (PASS == 1) {
      ((uint4*)feat_out)[(size_t)node * 16 + l16] = pack8(nw);
      float h[8];
      #pragma unroll
      for (int i = 0; i < 8; i++) h[i] = 0.5f * old[i] + 0.3f * nw[i];
      float4* hp = (float4*)(hi + (size_t)node * 128 + l16 * 8);
      hp[0] = make_float4(h[0], h[1], h[2], h[3]);
      hp[1] = make_float4(h[4], h[5], h[6], h[7]);
    } else {
      const float4* hp = (const float4*)(hi + (size_t)node * 128 + l16 * 8);
      float4 a = hp[0], b = hp[1];
      float h[8] = {a.x, a.y, a.z, a.w, b.x, b.y, b.z, b.w};
      #pragma unroll
      for (int i = 0; i < 8; i++) h[i] += 0.2f * nw[i];
      ((uint4*)ahi)[(size_t)node * 16 + l16] = pack8(h);
    }
  }
}

// ---------------- fused final GEMM via MFMA bf16 ------------------------------
// out = lrelu([ein | ahi | x] @ Wall + lin_b) + x0
// NO LDS, NO BARRIERS: B-fragments stream straight from global (wbt = 100 KB,
// L1/L2-resident chip-wide). The previous LDS version read the same 100 KB
// from L2 per block anyway but serialized it behind 8 barriers -> memory
// pipeline never filled (HBM 22%, MfmaUtil 4%, all pipes idle). Here every
// thread has ~120 independent loads for the scheduler to pipeline freely.
// A-fragments loaded per-kb (live range 1-2 frags, not 12).
__global__ __launch_bounds__(256)
void k_gemm2(const float* __restrict__ ein, const unsigned short* __restrict__ ahi,
             const float* __restrict__ x, const unsigned short* __restrict__ wbt,
             const float* __restrict__ lin_b, const float* __restrict__ x0,
             float* __restrict__ out) {
  int tid = threadIdx.x;
  int lane = tid & 63, wv = tid >> 6;
  int quad = lane >> 4, l16 = lane & 15;
  int n0 = blockIdx.x * 64;
  int rA = n0 + wv * 16 + l16;
  if (rA >= N_NODES) rA = N_NODES - 1;      // clamped dup; store-guarded
  int kq = quad * 8;

  f32x4 acc[8];
  #pragma unroll
  for (int i = 0; i < 8; i++) acc[i] = (f32x4){0.f, 0.f, 0.f, 0.f};

  // B fragment base for this lane: row (= output col) l16 + ct*16, col kb*32+kq
  const unsigned short* bp = wbt + (size_t)l16 * 392 + kq;

  #pragma unroll
  for (int kb = 0; kb < 12; kb++) {
    // ---- A fragment for this kb ----
    short8 a;
    if (kb < 4) {            // cols 0-127: ein (fp32 -> bf16)
      const float4* p = (const float4*)(ein + (size_t)rA * 128 + kb * 32 + kq);
      float4 u = p[0], v = p[1];
      a[0] = (short)f2bf(u.x); a[1] = (short)f2bf(u.y);
      a[2] = (short)f2bf(u.z); a[3] = (short)f2bf(u.w);
      a[4] = (short)f2bf(v.x); a[5] = (short)f2bf(v.y);
      a[6] = (short)f2bf(v.z); a[7] = (short)f2bf(v.w);
    } else if (kb < 8) {     // cols 128-255: ahi (bf16)
      a = *(const short8*)(ahi + (size_t)rA * 128 + (kb - 4) * 32 + kq);
    } else {                 // cols 256-383: x (fp32 -> bf16)
      const float4* p = (const float4*)(x + (size_t)rA * 128 + (kb - 8) * 32 + kq);
      float4 u = p[0], v = p[1];
      a[0] = (short)f2bf(u.x); a[1] = (short)f2bf(u.y);
      a[2] = (short)f2bf(u.z); a[3] = (short)f2bf(u.w);
      a[4] = (short)f2bf(v.x); a[5] = (short)f2bf(v.y);
      a[6] = (short)f2bf(v.z); a[7] = (short)f2bf(v.w);
    }
    // ---- 8 col-tiles, B direct from global ----
    #pragma unroll
    for (int ct = 0; ct < 8; ct++) {
      short8 b = *(const short8*)(bp + (size_t)ct * 16 * 392 + kb * 32);
      acc[ct] = __builtin_amdgcn_mfma_f32_16x16x32_bf16(a, b, acc[ct], 0, 0, 0);
    }
  }

  // ---- epilogue: +bias, lrelu, +x0 ----
  #pragma unroll
  for (int ct = 0; ct < 8; ct++) {
    int col = ct * 16 + l16;
    float bl = lin_b[col];
    #pragma unroll
    for (int r = 0; r < 4; r++) {
      int gn = n0 + wv * 16 + quad * 4 + r;
      if (gn < N_NODES) {
        float v = acc[ct][r] + bl;
        v = (v > 0.f) ? v : 0.01f * v;
        out[(size_t)gn * 128 + col] = v + x0[(size_t)gn * 128 + col];
      }
    }
  }
}

extern "C" void kernel_launch(void* const* d_in, const int* in_sizes, int n_in,
                              void* d_out, int out_size, void* d_ws, size_t ws_size,
                              hipStream_t stream) {
  const int*   src     = (const int*)d_in[0];
  const int*   dst     = (const int*)d_in[1];
  const float* x0      = (const float*)d_in[2];
  const float* x       = (const float*)d_in[3];
  const float* ein     = (const float*)d_in[4];
  const float* alpha   = (const float*)d_in[7];
  const float* emb     = (const float*)d_in[8];
  const float* w1      = (const float*)d_in[9];
  const float* b1      = (const float*)d_in[10];
  const float* w2      = (const float*)d_in[11];
  const float* b2      = (const float*)d_in[12];
  const float* weights = (const float*)d_in[13];
  const float* lin_w   = (const float*)d_in[14];
  const float* lin_b   = (const float*)d_in[15];
  float* out = (float*)d_out;

  // workspace layout (~82 MB)
  unsigned short* xk_bf  = (unsigned short*)d_ws;             // N*128 bf16
  unsigned short* xk1_bf = xk_bf  + (size_t)N_NODES * 128;
  unsigned short* ahi    = xk1_bf + (size_t)N_NODES * 128;
  unsigned short* wbt    = ahi    + (size_t)N_NODES * 128;    // 128*392 bf16
  float* dinv = (float*)(wbt + 128 * 392);
  int* degs   = (int*)(dinv + N_NODES);
  int* offs   = degs + N_NODES;
  int* cursor = offs + N_NODES;
  int* aux    = cursor + N_NODES;
  int* aux2   = aux + 512;
  int* csr    = aux2 + 512;

  hipMemsetAsync(degs, 0, sizeof(int) * 3 * (size_t)N_NODES, stream);

  int gN = (N_NODES + 255) / 256;   // 391
  int gE = (N_EDGES + 255) / 256;

  // fused: MLP + degree count + weight precompute (independent work, 1 dispatch)
  k_front<<<G_MLP + G_DEG + G_PRE, 256, 0, stream>>>(
      x, w1, w2, b1, b2, emb, alpha, xk_bf, dst, degs, weights, lin_w, wbt);

  k_scan1<<<gN, 256, 0, stream>>>(degs, offs, aux);
  k_scan2<<<1, 512, 0, stream>>>(aux, aux2, gN);
  k_scan3<<<gN, 256, 0, stream>>>(offs, aux2, degs, dinv);
  k_fill <<<gE, 256, 0, stream>>>(src, dst, offs, cursor, csr);

  float* hi = out;   // fp32 hi lives in d_out between pass1 and gemm
  k_gather<1><<<N_NODES / 4, 256, 0, stream>>>(xk_bf,  xk1_bf, hi, nullptr, csr, offs, degs, dinv);
  k_gather<2><<<N_NODES / 4, 256, 0, stream>>>(xk1_bf, nullptr, hi, ahi,    csr, offs, degs, dinv);

  k_gemm2<<<(N_NODES + 63) / 64, 256, 0, stream>>>(ein, ahi, x, wbt, lin_b, x0, out);
}

// Round 5
// 464.184 us; speedup vs baseline: 1.0564x; 1.0564x over previous
//
#include <hip/hip_runtime.h>

#define N_NODES 100000
#define N_EDGES 800000
#define D 128

// grid split for the fused front kernel
#define G_MLP 1563            // (N_NODES+63)/64
#define G_DEG 3125            // (N_EDGES+255)/256
#define G_PRE 192             // 384*128/256

typedef __attribute__((ext_vector_type(8))) short short8;
typedef __attribute__((ext_vector_type(4))) float f32x4;

__device__ inline unsigned short f2bf(float f) {
  unsigned u = __float_as_uint(f);
  unsigned r = (u + 0x7fffu + ((u >> 16) & 1u)) >> 16;
  return (unsigned short)r;
}
__device__ inline void bfma8(float* acc, const uint4 v, float d) {
  acc[0] = fmaf(__uint_as_float(v.x << 16), d, acc[0]);
  acc[1] = fmaf(__uint_as_float(v.x & 0xffff0000u), d, acc[1]);
  acc[2] = fmaf(__uint_as_float(v.y << 16), d, acc[2]);
  acc[3] = fmaf(__uint_as_float(v.y & 0xffff0000u), d, acc[3]);
  acc[4] = fmaf(__uint_as_float(v.z << 16), d, acc[4]);
  acc[5] = fmaf(__uint_as_float(v.z & 0xffff0000u), d, acc[5]);
  acc[6] = fmaf(__uint_as_float(v.w << 16), d, acc[6]);
  acc[7] = fmaf(__uint_as_float(v.w & 0xffff0000u), d, acc[7]);
}
__device__ inline void unpack8(float* o, const uint4 v) {
  o[0] = __uint_as_float(v.x << 16); o[1] = __uint_as_float(v.x & 0xffff0000u);
  o[2] = __uint_as_float(v.y << 16); o[3] = __uint_as_float(v.y & 0xffff0000u);
  o[4] = __uint_as_float(v.z << 16); o[5] = __uint_as_float(v.z & 0xffff0000u);
  o[6] = __uint_as_float(v.w << 16); o[7] = __uint_as_float(v.w & 0xffff0000u);
}
__device__ inline uint4 pack8(const float* v) {
  uint4 r;
  r.x = (unsigned)f2bf(v[0]) | ((unsigned)f2bf(v[1]) << 16);
  r.y = (unsigned)f2bf(v[2]) | ((unsigned)f2bf(v[3]) << 16);
  r.z = (unsigned)f2bf(v[4]) | ((unsigned)f2bf(v[5]) << 16);
  r.w = (unsigned)f2bf(v[6]) | ((unsigned)f2bf(v[7]) << 16);
  return r;
}

// ---------------- fused front: MLP (blocks 0..G_MLP) + degree count + wfr ----
// LDS ~25.6 KB (x staged per 32-K pass, like w1) -> 6 blocks/CU.
__global__ __launch_bounds__(256, 4)
void k_front(const float* __restrict__ x, const float* __restrict__ w1,
             const float* __restrict__ w2, const float* __restrict__ b1,
             const float* __restrict__ b2, const float* __restrict__ emb,
             const float* __restrict__ alpha_p, unsigned short* __restrict__ xk_bf,
             const int* __restrict__ dst, int* __restrict__ degs,
             const float* __restrict__ weights, const float* __restrict__ lin_w,
             unsigned short* __restrict__ wfr) {
  int tid = threadIdx.x;
  int bid = blockIdx.x;

  if (bid >= G_MLP) {
    if (bid < G_MLP + G_DEG) {
      // ---- degree count ----
      int e = (bid - G_MLP) * 256 + tid;
      if (e < N_EDGES) atomicAdd(&degs[dst[e]], 1);
    } else {
      // ---- precompute merged weights -> bf16, MFMA-FRAGMENT order ----
      // element (k in [0,384), d in [0,128)) of Wall^T goes to
      // wfr[(ct*12+kb)*512 + lane*8 + j], ct=d>>4, kb=k>>5,
      // lane=((k>>3)&3)*16 + (d&15), j=k&7.
      // -> each wave's B-fragment load in k_gemm2 is one contiguous 1KB burst.
      int gid = (bid - G_MLP - G_DEG) * 256 + tid;   // 384*128 threads
      int k = gid >> 7, d = gid & 127;
      float v;
      if (k < 128) {
        v = lin_w[d * 256 + k];
      } else {
        const float* wrow = weights + (k - 128) * 128;
        const float* lcol = lin_w + d * 256 + 128;
        float s = 0.f;
        for (int j = 0; j < 128; j++) s += wrow[j] * lcol[j];
        v = s;
      }
      int ct = d >> 4, kb = k >> 5;
      int lane = (((k >> 3) & 3) << 4) | (d & 15);
      int j = k & 7;
      wfr[((ct * 12 + kb) << 9) + (lane << 3) + j] = f2bf(v);
    }
    return;
  }

  // ---- per-node MLP -> prob -> xk(bf16) ----
  __shared__ __align__(16) float xsT[32 * 68];     // per-pass 32-K slice
  __shared__ __align__(16) float w1sT[32 * 128];
  __shared__ float zbuf[64];
  __shared__ float pbuf[64];

  int lane = tid & 63;
  int wave = tid >> 6;
  int n0 = bid * 64;

  int d8 = tid & 15;
  int n4 = tid >> 4;
  float acc[4][8];
  #pragma unroll
  for (int a = 0; a < 4; a++)
    #pragma unroll
    for (int c = 0; c < 8; c++) acc[a][c] = 0.f;

  for (int p = 0; p < 4; p++) {
    __syncthreads();
    {  // stage w1 K-slice, transposed: w1sT[k][j]
      int j = tid >> 1;
      int kg0 = (tid & 1) * 4;
      const float4* wr = (const float4*)(w1 + j * 128 + p * 32);
      #pragma unroll
      for (int c = 0; c < 4; c++) {
        float4 v = wr[kg0 + c];
        int k = (kg0 + c) * 4;
        w1sT[(k + 0) * 128 + j] = v.x;
        w1sT[(k + 1) * 128 + j] = v.y;
        w1sT[(k + 2) * 128 + j] = v.z;
        w1sT[(k + 3) * 128 + j] = v.w;
      }
    }
    {  // stage x K-slice, transposed: xsT[k][n] for k in [0,32)
      int n = lane;
      int gn = n0 + n;
      int k8 = wave * 8;
      const float4* xr = (const float4*)(x + (size_t)gn * 128 + p * 32 + k8);
      float4 v0 = make_float4(0.f, 0.f, 0.f, 0.f), v1 = v0;
      if (gn < N_NODES) { v0 = xr[0]; v1 = xr[1]; }
      xsT[(k8 + 0) * 68 + n] = v0.x;
      xsT[(k8 + 1) * 68 + n] = v0.y;
      xsT[(k8 + 2) * 68 + n] = v0.z;
      xsT[(k8 + 3) * 68 + n] = v0.w;
      xsT[(k8 + 4) * 68 + n] = v1.x;
      xsT[(k8 + 5) * 68 + n] = v1.y;
      xsT[(k8 + 6) * 68 + n] = v1.z;
      xsT[(k8 + 7) * 68 + n] = v1.w;
    }
    __syncthreads();

    for (int kk = 0; kk < 32; kk += 4) {
      float wq[4][8];
      float4 f[4];
      #pragma unroll
      for (int q = 0; q < 4; q++) {
        const float4* wr = (const float4*)(w1sT + (kk + q) * 128 + d8 * 8);
        float4 a = wr[0], b = wr[1];
        wq[q][0] = a.x; wq[q][1] = a.y; wq[q][2] = a.z; wq[q][3] = a.w;
        wq[q][4] = b.x; wq[q][5] = b.y; wq[q][6] = b.z; wq[q][7] = b.w;
        f[q] = *(const float4*)(xsT + (kk + q) * 68 + n4 * 4);
      }
      #pragma unroll
      for (int q = 0; q < 4; q++) {
        #pragma unroll
        for (int c = 0; c < 8; c++) {
          acc[0][c] += f[q].x * wq[q][c];
          acc[1][c] += f[q].y * wq[q][c];
          acc[2][c] += f[q].z * wq[q][c];
          acc[3][c] += f[q].w * wq[q][c];
        }
      }
    }
  }

  {
    int j0 = d8 * 8;
    float bb[8], wd[8];
    #pragma unroll
    for (int c = 0; c < 8; c++) {
      bb[c] = b1[j0 + c];
      wd[c] = w2[128 + j0 + c] - w2[j0 + c];
    }
    #pragma unroll
    for (int a = 0; a < 4; a++) {
      float s = 0.f;
      #pragma unroll
      for (int c = 0; c < 8; c++) {
        float h = fmaxf(acc[a][c] + bb[c], 0.f);
        s += h * wd[c];
      }
      s += __shfl_down(s, 8);
      s += __shfl_down(s, 4);
      s += __shfl_down(s, 2);
      s += __shfl_down(s, 1);
      if (d8 == 0) zbuf[n4 * 4 + a] = s;
    }
  }
  __syncthreads();
  if (tid < 64) {
    float db2 = b2[1] - b2[0];
    float z = zbuf[tid] + db2;
    pbuf[tid] = 1.f / (1.f + expf(-z));
  }
  __syncthreads();

  {
    float al = alpha_p[0];
    int d4 = tid & 31;
    const float4 e0 = ((const float4*)emb)[d4];
    const float4 e1 = ((const float4*)(emb + 128))[d4];
    #pragma unroll
    for (int i = 0; i < 8; i++) {
      int n = i * 8 + (tid >> 5);
      int gn = n0 + n;
      if (gn >= N_NODES) continue;
      float p = pbuf[n];
      float c0 = al * (1.f - p), c1 = al * p;
      float4 xv = ((const float4*)x)[(size_t)gn * 32 + d4];
      float o0 = xv.x + c0 * e0.x + c1 * e1.x;
      float o1 = xv.y + c0 * e0.y + c1 * e1.y;
      float o2 = xv.z + c0 * e0.z + c1 * e1.z;
      float o3 = xv.w + c0 * e0.w + c1 * e1.w;
      ushort4 ov = make_ushort4(f2bf(o0), f2bf(o1), f2bf(o2), f2bf(o3));
      ((ushort4*)xk_bf)[(size_t)gn * 32 + d4] = ov;
    }
  }
}

// ---------------- 2-level exclusive scan over degrees ----------------
__global__ void k_scan1(const int* __restrict__ degs, int* __restrict__ offs,
                        int* __restrict__ aux) {
  __shared__ int s[256];
  int tid = threadIdx.x;
  int i = blockIdx.x * 256 + tid;
  int v = (i < N_NODES) ? degs[i] : 0;
  int sum = v;
  s[tid] = sum; __syncthreads();
  for (int off = 1; off < 256; off <<= 1) {
    int t = (tid >= off) ? s[tid - off] : 0;
    __syncthreads();
    sum += t; s[tid] = sum;
    __syncthreads();
  }
  if (i < N_NODES) offs[i] = sum - v;
  if (tid == 255) aux[blockIdx.x] = sum;
}

__global__ void k_scan2(const int* __restrict__ aux, int* __restrict__ aux2, int nblk) {
  __shared__ int s[512];
  int tid = threadIdx.x;
  int v = (tid < nblk) ? aux[tid] : 0;
  int sum = v;
  s[tid] = sum; __syncthreads();
  for (int off = 1; off < 512; off <<= 1) {
    int t = (tid >= off) ? s[tid - off] : 0;
    __syncthreads();
    sum += t; s[tid] = sum;
    __syncthreads();
  }
  aux2[tid] = sum - v;
}

__global__ void k_scan3(int* __restrict__ offs, const int* __restrict__ aux2,
                        const int* __restrict__ degs, float* __restrict__ dinv) {
  int i = blockIdx.x * 256 + threadIdx.x;
  if (i < N_NODES) {
    offs[i] += aux2[blockIdx.x];
    dinv[i] = rsqrtf(fmaxf((float)degs[i], 1.0f));
  }
}

// ---------------- CSR fill (counting sort by dst) ----------------
__global__ void k_fill(const int* __restrict__ src, const int* __restrict__ dst,
                       const int* __restrict__ offs, int* __restrict__ cursor,
                       int* __restrict__ csr) {
  int e = blockIdx.x * 256 + threadIdx.x;
  if (e < N_EDGES) {
    int d = dst[e];
    int pos = offs[d] + atomicAdd(&cursor[d], 1);
    csr[pos] = src[e];
  }
}

// ---------------- Laplacian gather passes, bf16 feat, 4 edges/instr ----------
template <int PASS>
__global__ __launch_bounds__(256)
void k_gather(const unsigned short* __restrict__ feat,
              unsigned short* __restrict__ feat_out,
              float* __restrict__ hi,
              unsigned short* __restrict__ ahi,
              const int* __restrict__ csr, const int* __restrict__ offs,
              const int* __restrict__ degs, const float* __restrict__ dinv) {
  int node = blockIdx.x * 4 + (threadIdx.x >> 6);
  int lane = threadIdx.x & 63;
  int quad = lane >> 4;
  int l16 = lane & 15;
  int start = offs[node];
  int cnt = degs[node];
  const uint4* f16 = (const uint4*)feat;   // one row = 16 uint4
  float acc[8];
  #pragma unroll
  for (int i = 0; i < 8; i++) acc[i] = 0.f;

  int j = 0;
  for (; j + 8 <= cnt; j += 8) {            // 8 edges in flight
    int sa = csr[start + j + quad];
    int sb = csr[start + j + 4 + quad];
    float da = dinv[sa], db = dinv[sb];
    uint4 va = f16[(size_t)sa * 16 + l16];
    uint4 vb = f16[(size_t)sb * 16 + l16];
    bfma8(acc, va, da);
    bfma8(acc, vb, db);
  }
  if (j + 4 <= cnt) {
    int s = csr[start + j + quad];
    float d = dinv[s];
    uint4 v = f16[(size_t)s * 16 + l16];
    bfma8(acc, v, d);
    j += 4;
  }
  int rem = cnt - j;                        // 0..3
  if (quad < rem) {
    int s = csr[start + j + quad];
    float d = dinv[s];
    uint4 v = f16[(size_t)s * 16 + l16];
    bfma8(acc, v, d);
  }

  #pragma unroll
  for (int i = 0; i < 8; i++) {
    acc[i] += __shfl_down(acc[i], 32);
    acc[i] += __shfl_down(acc[i], 16);
  }

  if (quad == 0) {
    float dvi = dinv[node];
    float old[8], nw[8];
    unpack8(old, f16[(size_t)node * 16 + l16]);
    #pragma unroll
    for (int i = 0; i < 8; i++) nw[i] = old[i] - acc[i] * dvi;
    if (PASS == 1) {
      ((uint4*)feat_out)[(size_t)node * 16 + l16] = pack8(nw);
      float h[8];
      #pragma unroll
      for (int i = 0; i < 8; i++) h[i] = 0.5f * old[i] + 0.3f * nw[i];
      float4* hp = (float4*)(hi + (size_t)node * 128 + l16 * 8);
      hp[0] = make_float4(h[0], h[1], h[2], h[3]);
      hp[1] = make_float4(h[4], h[5], h[6], h[7]);
    } else {
      const float4* hp = (const float4*)(hi + (size_t)node * 128 + l16 * 8);
      float4 a = hp[0], b = hp[1];
      float h[8] = {a.x, a.y, a.z, a.w, b.x, b.y, b.z, b.w};
      #pragma unroll
      for (int i = 0; i < 8; i++) h[i] += 0.2f * nw[i];
      ((uint4*)ahi)[(size_t)node * 16 + l16] = pack8(h);
    }
  }
}

// ---------------- fused final GEMM via MFMA bf16 ------------------------------
// out = lrelu([ein | ahi | x] @ Wall + lin_b) + x0
// NO LDS, NO BARRIERS, and B in MFMA-FRAGMENT order: each wave's B-load is a
// single contiguous 1KB burst (lane*8 bf16), L2-resident (96 KB total).
// Round-4's failure was B at stride 784B -> 64 lines per load; this keeps the
// free pipelining but restores perfect coalescing.
__global__ __launch_bounds__(256)
void k_gemm2(const float* __restrict__ ein, const unsigned short* __restrict__ ahi,
             const float* __restrict__ x, const unsigned short* __restrict__ wfr,
             const float* __restrict__ lin_b, const float* __restrict__ x0,
             float* __restrict__ out) {
  int tid = threadIdx.x;
  int lane = tid & 63, wv = tid >> 6;
  int quad = lane >> 4, l16 = lane & 15;
  int n0 = blockIdx.x * 64;
  int rA = n0 + wv * 16 + l16;
  if (rA >= N_NODES) rA = N_NODES - 1;      // clamped dup; store-guarded
  int kq = quad * 8;

  f32x4 acc[8];
  #pragma unroll
  for (int i = 0; i < 8; i++) acc[i] = (f32x4){0.f, 0.f, 0.f, 0.f};

  const short8* bfrag = (const short8*)(wfr + (lane << 3));  // + frag*512

  #pragma unroll
  for (int kb = 0; kb < 12; kb++) {
    // ---- A fragment for this kb ----
    short8 a;
    if (kb < 4) {            // cols 0-127: ein (fp32 -> bf16)
      const float4* p = (const float4*)(ein + (size_t)rA * 128 + kb * 32 + kq);
      float4 u = p[0], v = p[1];
      a[0] = (short)f2bf(u.x); a[1] = (short)f2bf(u.y);
      a[2] = (short)f2bf(u.z); a[3] = (short)f2bf(u.w);
      a[4] = (short)f2bf(v.x); a[5] = (short)f2bf(v.y);
      a[6] = (short)f2bf(v.z); a[7] = (short)f2bf(v.w);
    } else if (kb < 8) {     // cols 128-255: ahi (bf16)
      a = *(const short8*)(ahi + (size_t)rA * 128 + (kb - 4) * 32 + kq);
    } else {                 // cols 256-383: x (fp32 -> bf16)
      const float4* p = (const float4*)(x + (size_t)rA * 128 + (kb - 8) * 32 + kq);
      float4 u = p[0], v = p[1];
      a[0] = (short)f2bf(u.x); a[1] = (short)f2bf(u.y);
      a[2] = (short)f2bf(u.z); a[3] = (short)f2bf(u.w);
      a[4] = (short)f2bf(v.x); a[5] = (short)f2bf(v.y);
      a[6] = (short)f2bf(v.z); a[7] = (short)f2bf(v.w);
    }
    // ---- 8 col-tiles, B fragment = coalesced 1KB burst from L2 ----
    #pragma unroll
    for (int ct = 0; ct < 8; ct++) {
      short8 b = bfrag[(ct * 12 + kb) << 6];   // frag*512 shorts = 64 short8
      acc[ct] = __builtin_amdgcn_mfma_f32_16x16x32_bf16(a, b, acc[ct], 0, 0, 0);
    }
  }

  // ---- epilogue: +bias, lrelu, +x0 ----
  #pragma unroll
  for (int ct = 0; ct < 8; ct++) {
    int col = ct * 16 + l16;
    float bl = lin_b[col];
    #pragma unroll
    for (int r = 0; r < 4; r++) {
      int gn = n0 + wv * 16 + quad * 4 + r;
      if (gn < N_NODES) {
        float v = acc[ct][r] + bl;
        v = (v > 0.f) ? v : 0.01f * v;
        out[(size_t)gn * 128 + col] = v + x0[(size_t)gn * 128 + col];
      }
    }
  }
}

extern "C" void kernel_launch(void* const* d_in, const int* in_sizes, int n_in,
                              void* d_out, int out_size, void* d_ws, size_t ws_size,
                              hipStream_t stream) {
  const int*   src     = (const int*)d_in[0];
  const int*   dst     = (const int*)d_in[1];
  const float* x0      = (const float*)d_in[2];
  const float* x       = (const float*)d_in[3];
  const float* ein     = (const float*)d_in[4];
  const float* alpha   = (const float*)d_in[7];
  const float* emb     = (const float*)d_in[8];
  const float* w1      = (const float*)d_in[9];
  const float* b1      = (const float*)d_in[10];
  const float* w2      = (const float*)d_in[11];
  const float* b2      = (const float*)d_in[12];
  const float* weights = (const float*)d_in[13];
  const float* lin_w   = (const float*)d_in[14];
  const float* lin_b   = (const float*)d_in[15];
  float* out = (float*)d_out;

  // workspace layout (~82 MB)
  unsigned short* xk_bf  = (unsigned short*)d_ws;             // N*128 bf16
  unsigned short* xk1_bf = xk_bf  + (size_t)N_NODES * 128;
  unsigned short* ahi    = xk1_bf + (size_t)N_NODES * 128;
  unsigned short* wfr    = ahi    + (size_t)N_NODES * 128;    // 96*512 bf16 frag-order
  float* dinv = (float*)(wfr + 128 * 392);
  int* degs   = (int*)(dinv + N_NODES);
  int* offs   = degs + N_NODES;
  int* cursor = offs + N_NODES;
  int* aux    = cursor + N_NODES;
  int* aux2   = aux + 512;
  int* csr    = aux2 + 512;

  hipMemsetAsync(degs, 0, sizeof(int) * 3 * (size_t)N_NODES, stream);

  int gN = (N_NODES + 255) / 256;   // 391
  int gE = (N_EDGES + 255) / 256;

  // fused: MLP + degree count + weight precompute (independent work, 1 dispatch)
  k_front<<<G_MLP + G_DEG + G_PRE, 256, 0, stream>>>(
      x, w1, w2, b1, b2, emb, alpha, xk_bf, dst, degs, weights, lin_w, wfr);

  k_scan1<<<gN, 256, 0, stream>>>(degs, offs, aux);
  k_scan2<<<1, 512, 0, stream>>>(aux, aux2, gN);
  k_scan3<<<gN, 256, 0, stream>>>(offs, aux2, degs, dinv);
  k_fill <<<gE, 256, 0, stream>>>(src, dst, offs, cursor, csr);

  float* hi = out;   // fp32 hi lives in d_out between pass1 and gemm
  k_gather<1><<<N_NODES / 4, 256, 0, stream>>>(xk_bf,  xk1_bf, hi, nullptr, csr, offs, degs, dinv);
  k_gather<2><<<N_NODES / 4, 256, 0, stream>>>(xk1_bf, nullptr, hi, ahi,    csr, offs, degs, dinv);

  k_gemm2<<<(N_NODES + 63) / 64, 256, 0, stream>>>(ein, ahi, x, wfr, lin_b, x0, out);
}

// Round 6
// 445.314 us; speedup vs baseline: 1.1012x; 1.0424x over previous
//
#include <hip/hip_runtime.h>

#define N_NODES 100000
#define N_EDGES 800000
#define D 128

// grid split for the fused front kernel
#define G_MLP 1563            // (N_NODES+63)/64
#define G_DEG 3125            // (N_EDGES+255)/256
#define G_PRE 192             // 384*128/256

typedef __attribute__((ext_vector_type(8))) short short8;
typedef __attribute__((ext_vector_type(4))) float f32x4;

__device__ inline unsigned short f2bf(float f) {
  unsigned u = __float_as_uint(f);
  unsigned r = (u + 0x7fffu + ((u >> 16) & 1u)) >> 16;
  return (unsigned short)r;
}
__device__ inline void bfma8(float* acc, const uint4 v, float d) {
  acc[0] = fmaf(__uint_as_float(v.x << 16), d, acc[0]);
  acc[1] = fmaf(__uint_as_float(v.x & 0xffff0000u), d, acc[1]);
  acc[2] = fmaf(__uint_as_float(v.y << 16), d, acc[2]);
  acc[3] = fmaf(__uint_as_float(v.y & 0xffff0000u), d, acc[3]);
  acc[4] = fmaf(__uint_as_float(v.z << 16), d, acc[4]);
  acc[5] = fmaf(__uint_as_float(v.z & 0xffff0000u), d, acc[5]);
  acc[6] = fmaf(__uint_as_float(v.w << 16), d, acc[6]);
  acc[7] = fmaf(__uint_as_float(v.w & 0xffff0000u), d, acc[7]);
}
__device__ inline void unpack8(float* o, const uint4 v) {
  o[0] = __uint_as_float(v.x << 16); o[1] = __uint_as_float(v.x & 0xffff0000u);
  o[2] = __uint_as_float(v.y << 16); o[3] = __uint_as_float(v.y & 0xffff0000u);
  o[4] = __uint_as_float(v.z << 16); o[5] = __uint_as_float(v.z & 0xffff0000u);
  o[6] = __uint_as_float(v.w << 16); o[7] = __uint_as_float(v.w & 0xffff0000u);
}
__device__ inline uint4 pack8(const float* v) {
  uint4 r;
  r.x = (unsigned)f2bf(v[0]) | ((unsigned)f2bf(v[1]) << 16);
  r.y = (unsigned)f2bf(v[2]) | ((unsigned)f2bf(v[3]) << 16);
  r.z = (unsigned)f2bf(v[4]) | ((unsigned)f2bf(v[5]) << 16);
  r.w = (unsigned)f2bf(v[6]) | ((unsigned)f2bf(v[7]) << 16);
  return r;
}

// ---------------- fused front: MLP (blocks 0..G_MLP) + degree count + wfr ----
// LDS ~25.6 KB (x staged per 32-K pass, like w1) -> 6 blocks/CU.
__global__ __launch_bounds__(256, 4)
void k_front(const float* __restrict__ x, const float* __restrict__ w1,
             const float* __restrict__ w2, const float* __restrict__ b1,
             const float* __restrict__ b2, const float* __restrict__ emb,
             const float* __restrict__ alpha_p, unsigned short* __restrict__ xk_bf,
             const int* __restrict__ dst, int* __restrict__ degs,
             const float* __restrict__ weights, const float* __restrict__ lin_w,
             unsigned short* __restrict__ wfr) {
  int tid = threadIdx.x;
  int bid = blockIdx.x;

  if (bid >= G_MLP) {
    if (bid < G_MLP + G_DEG) {
      // ---- degree count ----
      int e = (bid - G_MLP) * 256 + tid;
      if (e < N_EDGES) atomicAdd(&degs[dst[e]], 1);
    } else {
      // ---- precompute merged weights -> bf16, MFMA-FRAGMENT order ----
      // element (k in [0,384), d in [0,128)) of Wall^T goes to
      // wfr[(ct*12+kb)*512 + lane*8 + j], ct=d>>4, kb=k>>5,
      // lane=((k>>3)&3)*16 + (d&15), j=k&7.
      int gid = (bid - G_MLP - G_DEG) * 256 + tid;   // 384*128 threads
      int k = gid >> 7, d = gid & 127;
      float v;
      if (k < 128) {
        v = lin_w[d * 256 + k];
      } else {
        const float* wrow = weights + (k - 128) * 128;
        const float* lcol = lin_w + d * 256 + 128;
        float s = 0.f;
        for (int j = 0; j < 128; j++) s += wrow[j] * lcol[j];
        v = s;
      }
      int ct = d >> 4, kb = k >> 5;
      int lane = (((k >> 3) & 3) << 4) | (d & 15);
      int j = k & 7;
      wfr[((ct * 12 + kb) << 9) + (lane << 3) + j] = f2bf(v);
    }
    return;
  }

  // ---- per-node MLP -> prob -> xk(bf16) ----
  __shared__ __align__(16) float xsT[32 * 68];     // per-pass 32-K slice
  __shared__ __align__(16) float w1sT[32 * 128];
  __shared__ float zbuf[64];
  __shared__ float pbuf[64];

  int lane = tid & 63;
  int wave = tid >> 6;
  int n0 = bid * 64;

  int d8 = tid & 15;
  int n4 = tid >> 4;
  float acc[4][8];
  #pragma unroll
  for (int a = 0; a < 4; a++)
    #pragma unroll
    for (int c = 0; c < 8; c++) acc[a][c] = 0.f;

  for (int p = 0; p < 4; p++) {
    __syncthreads();
    {  // stage w1 K-slice, transposed: w1sT[k][j]
      int j = tid >> 1;
      int kg0 = (tid & 1) * 4;
      const float4* wr = (const float4*)(w1 + j * 128 + p * 32);
      #pragma unroll
      for (int c = 0; c < 4; c++) {
        float4 v = wr[kg0 + c];
        int k = (kg0 + c) * 4;
        w1sT[(k + 0) * 128 + j] = v.x;
        w1sT[(k + 1) * 128 + j] = v.y;
        w1sT[(k + 2) * 128 + j] = v.z;
        w1sT[(k + 3) * 128 + j] = v.w;
      }
    }
    {  // stage x K-slice, transposed: xsT[k][n] for k in [0,32)
      int n = lane;
      int gn = n0 + n;
      int k8 = wave * 8;
      const float4* xr = (const float4*)(x + (size_t)gn * 128 + p * 32 + k8);
      float4 v0 = make_float4(0.f, 0.f, 0.f, 0.f), v1 = v0;
      if (gn < N_NODES) { v0 = xr[0]; v1 = xr[1]; }
      xsT[(k8 + 0) * 68 + n] = v0.x;
      xsT[(k8 + 1) * 68 + n] = v0.y;
      xsT[(k8 + 2) * 68 + n] = v0.z;
      xsT[(k8 + 3) * 68 + n] = v0.w;
      xsT[(k8 + 4) * 68 + n] = v1.x;
      xsT[(k8 + 5) * 68 + n] = v1.y;
      xsT[(k8 + 6) * 68 + n] = v1.z;
      xsT[(k8 + 7) * 68 + n] = v1.w;
    }
    __syncthreads();

    for (int kk = 0; kk < 32; kk += 4) {
      float wq[4][8];
      float4 f[4];
      #pragma unroll
      for (int q = 0; q < 4; q++) {
        const float4* wr = (const float4*)(w1sT + (kk + q) * 128 + d8 * 8);
        float4 a = wr[0], b = wr[1];
        wq[q][0] = a.x; wq[q][1] = a.y; wq[q][2] = a.z; wq[q][3] = a.w;
        wq[q][4] = b.x; wq[q][5] = b.y; wq[q][6] = b.z; wq[q][7] = b.w;
        f[q] = *(const float4*)(xsT + (kk + q) * 68 + n4 * 4);
      }
      #pragma unroll
      for (int q = 0; q < 4; q++) {
        #pragma unroll
        for (int c = 0; c < 8; c++) {
          acc[0][c] += f[q].x * wq[q][c];
          acc[1][c] += f[q].y * wq[q][c];
          acc[2][c] += f[q].z * wq[q][c];
          acc[3][c] += f[q].w * wq[q][c];
        }
      }
    }
  }

  {
    int j0 = d8 * 8;
    float bb[8], wd[8];
    #pragma unroll
    for (int c = 0; c < 8; c++) {
      bb[c] = b1[j0 + c];
      wd[c] = w2[128 + j0 + c] - w2[j0 + c];
    }
    #pragma unroll
    for (int a = 0; a < 4; a++) {
      float s = 0.f;
      #pragma unroll
      for (int c = 0; c < 8; c++) {
        float h = fmaxf(acc[a][c] + bb[c], 0.f);
        s += h * wd[c];
      }
      s += __shfl_down(s, 8);
      s += __shfl_down(s, 4);
      s += __shfl_down(s, 2);
      s += __shfl_down(s, 1);
      if (d8 == 0) zbuf[n4 * 4 + a] = s;
    }
  }
  __syncthreads();
  if (tid < 64) {
    float db2 = b2[1] - b2[0];
    float z = zbuf[tid] + db2;
    pbuf[tid] = 1.f / (1.f + expf(-z));
  }
  __syncthreads();

  {
    float al = alpha_p[0];
    int d4 = tid & 31;
    const float4 e0 = ((const float4*)emb)[d4];
    const float4 e1 = ((const float4*)(emb + 128))[d4];
    #pragma unroll
    for (int i = 0; i < 8; i++) {
      int n = i * 8 + (tid >> 5);
      int gn = n0 + n;
      if (gn >= N_NODES) continue;
      float p = pbuf[n];
      float c0 = al * (1.f - p), c1 = al * p;
      float4 xv = ((const float4*)x)[(size_t)gn * 32 + d4];
      float o0 = xv.x + c0 * e0.x + c1 * e1.x;
      float o1 = xv.y + c0 * e0.y + c1 * e1.y;
      float o2 = xv.z + c0 * e0.z + c1 * e1.z;
      float o3 = xv.w + c0 * e0.w + c1 * e1.w;
      ushort4 ov = make_ushort4(f2bf(o0), f2bf(o1), f2bf(o2), f2bf(o3));
      ((ushort4*)xk_bf)[(size_t)gn * 32 + d4] = ov;
    }
  }
}

// ---------------- 2-level exclusive scan over degrees ----------------
__global__ void k_scan1(const int* __restrict__ degs, int* __restrict__ offs,
                        int* __restrict__ aux) {
  __shared__ int s[256];
  int tid = threadIdx.x;
  int i = blockIdx.x * 256 + tid;
  int v = (i < N_NODES) ? degs[i] : 0;
  int sum = v;
  s[tid] = sum; __syncthreads();
  for (int off = 1; off < 256; off <<= 1) {
    int t = (tid >= off) ? s[tid - off] : 0;
    __syncthreads();
    sum += t; s[tid] = sum;
    __syncthreads();
  }
  if (i < N_NODES) offs[i] = sum - v;
  if (tid == 255) aux[blockIdx.x] = sum;
}

__global__ void k_scan2(const int* __restrict__ aux, int* __restrict__ aux2, int nblk) {
  __shared__ int s[512];
  int tid = threadIdx.x;
  int v = (tid < nblk) ? aux[tid] : 0;
  int sum = v;
  s[tid] = sum; __syncthreads();
  for (int off = 1; off < 512; off <<= 1) {
    int t = (tid >= off) ? s[tid - off] : 0;
    __syncthreads();
    sum += t; s[tid] = sum;
    __syncthreads();
  }
  aux2[tid] = sum - v;
}

__global__ void k_scan3(int* __restrict__ offs, const int* __restrict__ aux2,
                        const int* __restrict__ degs, float* __restrict__ dinv) {
  int i = blockIdx.x * 256 + threadIdx.x;
  if (i < N_NODES) {
    offs[i] += aux2[blockIdx.x];
    dinv[i] = rsqrtf(fmaxf((float)degs[i], 1.0f));
  }
}

// ---------------- CSR fill (counting sort by dst) ----------------
__global__ void k_fill(const int* __restrict__ src, const int* __restrict__ dst,
                       const int* __restrict__ offs, int* __restrict__ cursor,
                       int* __restrict__ csr) {
  int e = blockIdx.x * 256 + threadIdx.x;
  if (e < N_EDGES) {
    int d = dst[e];
    int pos = offs[d] + atomicAdd(&cursor[d], 1);
    csr[pos] = src[e];
  }
}

// ---------------- Laplacian gather passes, bf16 feat, 4 edges/instr ----------
template <int PASS>
__global__ __launch_bounds__(256)
void k_gather(const unsigned short* __restrict__ feat,
              unsigned short* __restrict__ feat_out,
              float* __restrict__ hi,
              unsigned short* __restrict__ ahi,
              const int* __restrict__ csr, const int* __restrict__ offs,
              const int* __restrict__ degs, const float* __restrict__ dinv) {
  int node = blockIdx.x * 4 + (threadIdx.x >> 6);
  int lane = threadIdx.x & 63;
  int quad = lane >> 4;
  int l16 = lane & 15;
  int start = offs[node];
  int cnt = degs[node];
  const uint4* f16 = (const uint4*)feat;   // one row = 16 uint4
  float acc[8];
  #pragma unroll
  for (int i = 0; i < 8; i++) acc[i] = 0.f;

  int j = 0;
  for (; j + 8 <= cnt; j += 8) {            // 8 edges in flight
    int sa = csr[start + j + quad];
    int sb = csr[start + j + 4 + quad];
    float da = dinv[sa], db = dinv[sb];
    uint4 va = f16[(size_t)sa * 16 + l16];
    uint4 vb = f16[(size_t)sb * 16 + l16];
    bfma8(acc, va, da);
    bfma8(acc, vb, db);
  }
  if (j + 4 <= cnt) {
    int s = csr[start + j + quad];
    float d = dinv[s];
    uint4 v = f16[(size_t)s * 16 + l16];
    bfma8(acc, v, d);
    j += 4;
  }
  int rem = cnt - j;                        // 0..3
  if (quad < rem) {
    int s = csr[start + j + quad];
    float d = dinv[s];
    uint4 v = f16[(size_t)s * 16 + l16];
    bfma8(acc, v, d);
  }

  #pragma unroll
  for (int i = 0; i < 8; i++) {
    acc[i] += __shfl_down(acc[i], 32);
    acc[i] += __shfl_down(acc[i], 16);
  }

  if (quad == 0) {
    float dvi = dinv[node];
    float old[8], nw[8];
    unpack8(old, f16[(size_t)node * 16 + l16]);
    #pragma unroll
    for (int i = 0; i < 8; i++) nw[i] = old[i] - acc[i] * dvi;
    if (PASS == 1) {
      ((uint4*)feat_out)[(size_t)node * 16 + l16] = pack8(nw);
      float h[8];
      #pragma unroll
      for (int i = 0; i < 8; i++) h[i] = 0.5f * old[i] + 0.3f * nw[i];
      float4* hp = (float4*)(hi + (size_t)node * 128 + l16 * 8);
      hp[0] = make_float4(h[0], h[1], h[2], h[3]);
      hp[1] = make_float4(h[4], h[5], h[6], h[7]);
    } else {
      const float4* hp = (const float4*)(hi + (size_t)node * 128 + l16 * 8);
      float4 a = hp[0], b = hp[1];
      float h[8] = {a.x, a.y, a.z, a.w, b.x, b.y, b.z, b.w};
      #pragma unroll
      for (int i = 0; i < 8; i++) h[i] += 0.2f * nw[i];
      ((uint4*)ahi)[(size_t)node * 16 + l16] = pack8(h);
    }
  }
}

// ---------------- fused final GEMM via MFMA bf16 ------------------------------
// out = lrelu([ein | ahi | x] @ Wall + lin_b) + x0
// B (fragment-ordered wfr, 96KB) staged through DOUBLE-BUFFERED LDS in four
// 24KB chunks (48KB total -> 3 blocks/CU). Staging is a linear coalesced copy;
// LDS reads are lane-contiguous 1KB bursts (zero bank conflicts, vs 2.4M with
// the 392-stride layout). T14 async split: issue next chunk's global loads,
// run 24 MFMAs on current chunk (hides L2 latency), then ds_write + ONE barrier
// per chunk (round 3 had 2 barriers + no overlap).
__global__ __launch_bounds__(256)
void k_gemm2(const float* __restrict__ ein, const unsigned short* __restrict__ ahi,
             const float* __restrict__ x, const unsigned short* __restrict__ wfr,
             const float* __restrict__ lin_b, const float* __restrict__ x0,
             float* __restrict__ out) {
  __shared__ __align__(16) unsigned short Bs[2][24 * 512];
  int tid = threadIdx.x;
  int lane = tid & 63, wv = tid >> 6;
  int quad = lane >> 4, l16 = lane & 15;
  int n0 = blockIdx.x * 64;
  int rA = n0 + wv * 16 + l16;
  if (rA >= N_NODES) rA = N_NODES - 1;      // clamped dup; store-guarded
  int kq = quad * 8;

  // ---- 12 a_frags in registers (A row = rA) ----
  short8 af[12];
  #pragma unroll
  for (int kb = 0; kb < 4; kb++) {          // cols 0-127: ein (fp32 -> bf16)
    const float4* p = (const float4*)(ein + (size_t)rA * 128 + kb * 32 + kq);
    float4 a = p[0], b = p[1];
    short8 t;
    t[0] = (short)f2bf(a.x); t[1] = (short)f2bf(a.y);
    t[2] = (short)f2bf(a.z); t[3] = (short)f2bf(a.w);
    t[4] = (short)f2bf(b.x); t[5] = (short)f2bf(b.y);
    t[6] = (short)f2bf(b.z); t[7] = (short)f2bf(b.w);
    af[kb] = t;
  }
  #pragma unroll
  for (int kb = 0; kb < 4; kb++)            // cols 128-255: ahi (bf16)
    af[4 + kb] = *(const short8*)(ahi + (size_t)rA * 128 + kb * 32 + kq);
  #pragma unroll
  for (int kb = 0; kb < 4; kb++) {          // cols 256-383: x (fp32 -> bf16)
    const float4* p = (const float4*)(x + (size_t)rA * 128 + kb * 32 + kq);
    float4 a = p[0], b = p[1];
    short8 t;
    t[0] = (short)f2bf(a.x); t[1] = (short)f2bf(a.y);
    t[2] = (short)f2bf(a.z); t[3] = (short)f2bf(a.w);
    t[4] = (short)f2bf(b.x); t[5] = (short)f2bf(b.y);
    t[6] = (short)f2bf(b.z); t[7] = (short)f2bf(b.w);
    af[8 + kb] = t;
  }

  f32x4 acc[8];
  #pragma unroll
  for (int i = 0; i < 8; i++) acc[i] = (f32x4){0.f, 0.f, 0.f, 0.f};

  const uint4* W4 = (const uint4*)wfr;      // 6144 uint4 total, 1536/chunk

  // ---- prologue: stage chunk 0 ----
  {
    uint4 tmp[6];
    #pragma unroll
    for (int i = 0; i < 6; i++) tmp[i] = W4[tid + i * 256];
    uint4* B4 = (uint4*)Bs[0];
    #pragma unroll
    for (int i = 0; i < 6; i++) B4[tid + i * 256] = tmp[i];
  }
  __syncthreads();

  #pragma unroll
  for (int ch = 0; ch < 4; ch++) {
    int cur = ch & 1;
    // issue next chunk's global loads (in flight across the MFMAs below)
    uint4 tmp[6];
    if (ch < 3) {
      #pragma unroll
      for (int i = 0; i < 6; i++) tmp[i] = W4[(ch + 1) * 1536 + tid + i * 256];
    }
    // compute on current chunk: 2 col-tiles x 12 kb
    const unsigned short* Bc = Bs[cur];
    #pragma unroll
    for (int ctl = 0; ctl < 2; ctl++) {
      #pragma unroll
      for (int kb = 0; kb < 12; kb++) {
        short8 b = *(const short8*)(Bc + (ctl * 12 + kb) * 512 + (lane << 3));
        acc[ch * 2 + ctl] =
            __builtin_amdgcn_mfma_f32_16x16x32_bf16(af[kb], b, acc[ch * 2 + ctl], 0, 0, 0);
      }
    }
    // write next chunk and publish with a single barrier
    if (ch < 3) {
      uint4* B4 = (uint4*)Bs[cur ^ 1];
      #pragma unroll
      for (int i = 0; i < 6; i++) B4[tid + i * 256] = tmp[i];
      __syncthreads();
    }
  }

  // ---- epilogue: +bias, lrelu, +x0 ----
  #pragma unroll
  for (int ct = 0; ct < 8; ct++) {
    int col = ct * 16 + l16;
    float bl = lin_b[col];
    #pragma unroll
    for (int r = 0; r < 4; r++) {
      int gn = n0 + wv * 16 + quad * 4 + r;
      if (gn < N_NODES) {
        float v = acc[ct][r] + bl;
        v = (v > 0.f) ? v : 0.01f * v;
        out[(size_t)gn * 128 + col] = v + x0[(size_t)gn * 128 + col];
      }
    }
  }
}

extern "C" void kernel_launch(void* const* d_in, const int* in_sizes, int n_in,
                              void* d_out, int out_size, void* d_ws, size_t ws_size,
                              hipStream_t stream) {
  const int*   src     = (const int*)d_in[0];
  const int*   dst     = (const int*)d_in[1];
  const float* x0      = (const float*)d_in[2];
  const float* x       = (const float*)d_in[3];
  const float* ein     = (const float*)d_in[4];
  const float* alpha   = (const float*)d_in[7];
  const float* emb     = (const float*)d_in[8];
  const float* w1      = (const float*)d_in[9];
  const float* b1      = (const float*)d_in[10];
  const float* w2      = (const float*)d_in[11];
  const float* b2      = (const float*)d_in[12];
  const float* weights = (const float*)d_in[13];
  const float* lin_w   = (const float*)d_in[14];
  const float* lin_b   = (const float*)d_in[15];
  float* out = (float*)d_out;

  // workspace layout (~82 MB)
  unsigned short* xk_bf  = (unsigned short*)d_ws;             // N*128 bf16
  unsigned short* xk1_bf = xk_bf  + (size_t)N_NODES * 128;
  unsigned short* ahi    = xk1_bf + (size_t)N_NODES * 128;
  unsigned short* wfr    = ahi    + (size_t)N_NODES * 128;    // 96*512 bf16 frag-order
  float* dinv = (float*)(wfr + 128 * 392);
  int* degs   = (int*)(dinv + N_NODES);
  int* offs   = degs + N_NODES;
  int* cursor = offs + N_NODES;
  int* aux    = cursor + N_NODES;
  int* aux2   = aux + 512;
  int* csr    = aux2 + 512;

  hipMemsetAsync(degs, 0, sizeof(int) * 3 * (size_t)N_NODES, stream);

  int gN = (N_NODES + 255) / 256;   // 391
  int gE = (N_EDGES + 255) / 256;

  // fused: MLP + degree count + weight precompute (independent work, 1 dispatch)
  k_front<<<G_MLP + G_DEG + G_PRE, 256, 0, stream>>>(
      x, w1, w2, b1, b2, emb, alpha, xk_bf, dst, degs, weights, lin_w, wfr);

  k_scan1<<<gN, 256, 0, stream>>>(degs, offs, aux);
  k_scan2<<<1, 512, 0, stream>>>(aux, aux2, gN);
  k_scan3<<<gN, 256, 0, stream>>>(offs, aux2, degs, dinv);
  k_fill <<<gE, 256, 0, stream>>>(src, dst, offs, cursor, csr);

  float* hi = out;   // fp32 hi lives in d_out between pass1 and gemm
  k_gather<1><<<N_NODES / 4, 256, 0, stream>>>(xk_bf,  xk1_bf, hi, nullptr, csr, offs, degs, dinv);
  k_gather<2><<<N_NODES / 4, 256, 0, stream>>>(xk1_bf, nullptr, hi, ahi,    csr, offs, degs, dinv);

  k_gemm2<<<(N_NODES + 63) / 64, 256, 0, stream>>>(ein, ahi, x, wfr, lin_b, x0, out);
}

// Round 7
// 435.177 us; speedup vs baseline: 1.1269x; 1.0233x over previous
//
#include <hip/hip_runtime.h>

#define N_NODES 100000
#define N_EDGES 800000
#define D 128

// grid split for the fused front kernel
#define G_MLP 782             // (N_NODES+127)/128
#define G_DEG 3125            // (N_EDGES+255)/256
#define G_PRE 192             // 384*128/256

typedef __attribute__((ext_vector_type(8))) short short8;
typedef __attribute__((ext_vector_type(4))) float f32x4;

__device__ inline unsigned short f2bf(float f) {
  unsigned u = __float_as_uint(f);
  unsigned r = (u + 0x7fffu + ((u >> 16) & 1u)) >> 16;
  return (unsigned short)r;
}
__device__ inline void bfma8(float* acc, const uint4 v, float d) {
  acc[0] = fmaf(__uint_as_float(v.x << 16), d, acc[0]);
  acc[1] = fmaf(__uint_as_float(v.x & 0xffff0000u), d, acc[1]);
  acc[2] = fmaf(__uint_as_float(v.y << 16), d, acc[2]);
  acc[3] = fmaf(__uint_as_float(v.y & 0xffff0000u), d, acc[3]);
  acc[4] = fmaf(__uint_as_float(v.z << 16), d, acc[4]);
  acc[5] = fmaf(__uint_as_float(v.z & 0xffff0000u), d, acc[5]);
  acc[6] = fmaf(__uint_as_float(v.w << 16), d, acc[6]);
  acc[7] = fmaf(__uint_as_float(v.w & 0xffff0000u), d, acc[7]);
}
__device__ inline void unpack8(float* o, const uint4 v) {
  o[0] = __uint_as_float(v.x << 16); o[1] = __uint_as_float(v.x & 0xffff0000u);
  o[2] = __uint_as_float(v.y << 16); o[3] = __uint_as_float(v.y & 0xffff0000u);
  o[4] = __uint_as_float(v.z << 16); o[5] = __uint_as_float(v.z & 0xffff0000u);
  o[6] = __uint_as_float(v.w << 16); o[7] = __uint_as_float(v.w & 0xffff0000u);
}
__device__ inline uint4 pack8(const float* v) {
  uint4 r;
  r.x = (unsigned)f2bf(v[0]) | ((unsigned)f2bf(v[1]) << 16);
  r.y = (unsigned)f2bf(v[2]) | ((unsigned)f2bf(v[3]) << 16);
  r.z = (unsigned)f2bf(v[4]) | ((unsigned)f2bf(v[5]) << 16);
  r.w = (unsigned)f2bf(v[6]) | ((unsigned)f2bf(v[7]) << 16);
  return r;
}

// ---------------- fused front: MLP (blocks 0..G_MLP) + degree count + wfr ----
// MLP: 128 nodes/block (halves w1 restaging vs 64), acc[8 nodes][8 dims]/thread
// (halves LDS-reads per FMA). w1sT uses a j-dependent swizzle (row 140,
// dim j at j+(j>>5)*4) so the wq ds_read_b128 is 2-way (free) instead of the
// 4-way conflict of the plain stride-128 layout (7.2M conflict cycles).
__global__ __launch_bounds__(256, 4)
void k_front(const float* __restrict__ x, const float* __restrict__ w1,
             const float* __restrict__ w2, const float* __restrict__ b1,
             const float* __restrict__ b2, const float* __restrict__ emb,
             const float* __restrict__ alpha_p, unsigned short* __restrict__ xk_bf,
             const int* __restrict__ dst, int* __restrict__ degs,
             const float* __restrict__ weights, const float* __restrict__ lin_w,
             unsigned short* __restrict__ wfr) {
  int tid = threadIdx.x;
  int bid = blockIdx.x;

  if (bid >= G_MLP) {
    if (bid < G_MLP + G_DEG) {
      // ---- degree count ----
      int e = (bid - G_MLP) * 256 + tid;
      if (e < N_EDGES) atomicAdd(&degs[dst[e]], 1);
    } else {
      // ---- precompute merged weights -> bf16, MFMA-FRAGMENT order ----
      int gid = (bid - G_MLP - G_DEG) * 256 + tid;   // 384*128 threads
      int k = gid >> 7, d = gid & 127;
      float v;
      if (k < 128) {
        v = lin_w[d * 256 + k];
      } else {
        const float* wrow = weights + (k - 128) * 128;
        const float* lcol = lin_w + d * 256 + 128;
        float s = 0.f;
        for (int j = 0; j < 128; j++) s += wrow[j] * lcol[j];
        v = s;
      }
      int ct = d >> 4, kb = k >> 5;
      int lane = (((k >> 3) & 3) << 4) | (d & 15);
      int j = k & 7;
      wfr[((ct * 12 + kb) << 9) + (lane << 3) + j] = f2bf(v);
    }
    return;
  }

  // ---- per-node MLP -> prob -> xk(bf16), 128 nodes/block ----
  __shared__ __align__(16) float w1sT[32 * 140];   // swizzled: dim j at j+(j>>5)*4
  __shared__ __align__(16) float xsT[32 * 132];    // [k][node]
  __shared__ float zbuf[128];
  __shared__ float pbuf[128];

  int n0 = bid * 128;
  int d8 = tid & 15;        // 8-dim group
  int n8 = tid >> 4;        // 8-node group
  int woff = d8 * 8 + ((d8 >> 2) << 2);   // swizzled read offset into w1sT row

  float acc[8][8];
  #pragma unroll
  for (int a = 0; a < 8; a++)
    #pragma unroll
    for (int c = 0; c < 8; c++) acc[a][c] = 0.f;

  for (int p = 0; p < 4; p++) {
    __syncthreads();
    {  // stage w1 K-slice, transposed+swizzled: w1sT[k][off(j)]
      int j = tid >> 1;
      int kg0 = (tid & 1) * 4;
      int offj = j + ((j >> 5) << 2);
      const float4* wr = (const float4*)(w1 + j * 128 + p * 32);
      #pragma unroll
      for (int c = 0; c < 4; c++) {
        float4 v = wr[kg0 + c];
        int k = (kg0 + c) * 4;
        w1sT[(k + 0) * 140 + offj] = v.x;
        w1sT[(k + 1) * 140 + offj] = v.y;
        w1sT[(k + 2) * 140 + offj] = v.z;
        w1sT[(k + 3) * 140 + offj] = v.w;
      }
    }
    {  // stage x K-slice, transposed: xsT[k][n], 128 nodes x 32 k
      int n = tid & 127;
      int kh = tid >> 7;          // 0/1: which 16-k half
      int gn = n0 + n;
      const float4* xr = (const float4*)(x + (size_t)gn * 128 + p * 32 + kh * 16);
      #pragma unroll
      for (int i = 0; i < 4; i++) {
        float4 v = make_float4(0.f, 0.f, 0.f, 0.f);
        if (gn < N_NODES) v = xr[i];
        int k = kh * 16 + i * 4;
        xsT[(k + 0) * 132 + n] = v.x;
        xsT[(k + 1) * 132 + n] = v.y;
        xsT[(k + 2) * 132 + n] = v.z;
        xsT[(k + 3) * 132 + n] = v.w;
      }
    }
    __syncthreads();

    #pragma unroll 4
    for (int kk = 0; kk < 32; kk++) {
      const float4* wp = (const float4*)(w1sT + kk * 140 + woff);
      float4 wa = wp[0], wb = wp[1];
      const float4* fp = (const float4*)(xsT + kk * 132 + n8 * 8);
      float4 fa = fp[0], fb = fp[1];
      float w[8] = {wa.x, wa.y, wa.z, wa.w, wb.x, wb.y, wb.z, wb.w};
      float f[8] = {fa.x, fa.y, fa.z, fa.w, fb.x, fb.y, fb.z, fb.w};
      #pragma unroll
      for (int a = 0; a < 8; a++)
        #pragma unroll
        for (int c = 0; c < 8; c++)
          acc[a][c] = fmaf(f[a], w[c], acc[a][c]);
    }
  }

  {
    int j0 = d8 * 8;
    float bb[8], wd[8];
    #pragma unroll
    for (int c = 0; c < 8; c++) {
      bb[c] = b1[j0 + c];
      wd[c] = w2[128 + j0 + c] - w2[j0 + c];
    }
    #pragma unroll
    for (int a = 0; a < 8; a++) {
      float s = 0.f;
      #pragma unroll
      for (int c = 0; c < 8; c++) {
        float h = fmaxf(acc[a][c] + bb[c], 0.f);
        s += h * wd[c];
      }
      s += __shfl_down(s, 8);
      s += __shfl_down(s, 4);
      s += __shfl_down(s, 2);
      s += __shfl_down(s, 1);
      if (d8 == 0) zbuf[n8 * 8 + a] = s;
    }
  }
  __syncthreads();
  if (tid < 128) {
    float db2 = b2[1] - b2[0];
    float z = zbuf[tid] + db2;
    pbuf[tid] = 1.f / (1.f + expf(-z));
  }
  __syncthreads();

  {
    float al = alpha_p[0];
    int d4 = tid & 31;
    const float4 e0 = ((const float4*)emb)[d4];
    const float4 e1 = ((const float4*)(emb + 128))[d4];
    #pragma unroll
    for (int i = 0; i < 16; i++) {
      int n = i * 8 + (tid >> 5);
      int gn = n0 + n;
      if (gn >= N_NODES) continue;
      float p = pbuf[n];
      float c0 = al * (1.f - p), c1 = al * p;
      float4 xv = ((const float4*)x)[(size_t)gn * 32 + d4];
      float o0 = xv.x + c0 * e0.x + c1 * e1.x;
      float o1 = xv.y + c0 * e0.y + c1 * e1.y;
      float o2 = xv.z + c0 * e0.z + c1 * e1.z;
      float o3 = xv.w + c0 * e0.w + c1 * e1.w;
      ushort4 ov = make_ushort4(f2bf(o0), f2bf(o1), f2bf(o2), f2bf(o3));
      ((ushort4*)xk_bf)[(size_t)gn * 32 + d4] = ov;
    }
  }
}

// ---------------- 2-level exclusive scan over degrees ----------------
__global__ void k_scan1(const int* __restrict__ degs, int* __restrict__ offs,
                        int* __restrict__ aux) {
  __shared__ int s[256];
  int tid = threadIdx.x;
  int i = blockIdx.x * 256 + tid;
  int v = (i < N_NODES) ? degs[i] : 0;
  int sum = v;
  s[tid] = sum; __syncthreads();
  for (int off = 1; off < 256; off <<= 1) {
    int t = (tid >= off) ? s[tid - off] : 0;
    __syncthreads();
    sum += t; s[tid] = sum;
    __syncthreads();
  }
  if (i < N_NODES) offs[i] = sum - v;
  if (tid == 255) aux[blockIdx.x] = sum;
}

__global__ void k_scan2(const int* __restrict__ aux, int* __restrict__ aux2, int nblk) {
  __shared__ int s[512];
  int tid = threadIdx.x;
  int v = (tid < nblk) ? aux[tid] : 0;
  int sum = v;
  s[tid] = sum; __syncthreads();
  for (int off = 1; off < 512; off <<= 1) {
    int t = (tid >= off) ? s[tid - off] : 0;
    __syncthreads();
    sum += t; s[tid] = sum;
    __syncthreads();
  }
  aux2[tid] = sum - v;
}

__global__ void k_scan3(int* __restrict__ offs, const int* __restrict__ aux2,
                        const int* __restrict__ degs, float* __restrict__ dinv) {
  int i = blockIdx.x * 256 + threadIdx.x;
  if (i < N_NODES) {
    offs[i] += aux2[blockIdx.x];
    dinv[i] = rsqrtf(fmaxf((float)degs[i], 1.0f));
  }
}

// ---------------- CSR fill (counting sort by dst) ----------------
__global__ void k_fill(const int* __restrict__ src, const int* __restrict__ dst,
                       const int* __restrict__ offs, int* __restrict__ cursor,
                       int* __restrict__ csr) {
  int e = blockIdx.x * 256 + threadIdx.x;
  if (e < N_EDGES) {
    int d = dst[e];
    int pos = offs[d] + atomicAdd(&cursor[d], 1);
    csr[pos] = src[e];
  }
}

// ---------------- Laplacian gather passes, bf16 feat, 4 edges/instr ----------
template <int PASS>
__global__ __launch_bounds__(256)
void k_gather(const unsigned short* __restrict__ feat,
              unsigned short* __restrict__ feat_out,
              float* __restrict__ hi,
              unsigned short* __restrict__ ahi,
              const int* __restrict__ csr, const int* __restrict__ offs,
              const int* __restrict__ degs, const float* __restrict__ dinv) {
  int node = blockIdx.x * 4 + (threadIdx.x >> 6);
  int lane = threadIdx.x & 63;
  int quad = lane >> 4;
  int l16 = lane & 15;
  int start = offs[node];
  int cnt = degs[node];
  const uint4* f16 = (const uint4*)feat;   // one row = 16 uint4
  float acc[8];
  #pragma unroll
  for (int i = 0; i < 8; i++) acc[i] = 0.f;

  int j = 0;
  for (; j + 8 <= cnt; j += 8) {            // 8 edges in flight
    int sa = csr[start + j + quad];
    int sb = csr[start + j + 4 + quad];
    float da = dinv[sa], db = dinv[sb];
    uint4 va = f16[(size_t)sa * 16 + l16];
    uint4 vb = f16[(size_t)sb * 16 + l16];
    bfma8(acc, va, da);
    bfma8(acc, vb, db);
  }
  if (j + 4 <= cnt) {
    int s = csr[start + j + quad];
    float d = dinv[s];
    uint4 v = f16[(size_t)s * 16 + l16];
    bfma8(acc, v, d);
    j += 4;
  }
  int rem = cnt - j;                        // 0..3
  if (quad < rem) {
    int s = csr[start + j + quad];
    float d = dinv[s];
    uint4 v = f16[(size_t)s * 16 + l16];
    bfma8(acc, v, d);
  }

  #pragma unroll
  for (int i = 0; i < 8; i++) {
    acc[i] += __shfl_down(acc[i], 32);
    acc[i] += __shfl_down(acc[i], 16);
  }

  if (quad == 0) {
    float dvi = dinv[node];
    float old[8], nw[8];
    unpack8(old, f16[(size_t)node * 16 + l16]);
    #pragma unroll
    for (int i = 0; i < 8; i++) nw[i] = old[i] - acc[i] * dvi;
    if (PASS == 1) {
      ((uint4*)feat_out)[(size_t)node * 16 + l16] = pack8(nw);
      float h[8];
      #pragma unroll
      for (int i = 0; i < 8; i++) h[i] = 0.5f * old[i] + 0.3f * nw[i];
      float4* hp = (float4*)(hi + (size_t)node * 128 + l16 * 8);
      hp[0] = make_float4(h[0], h[1], h[2], h[3]);
      hp[1] = make_float4(h[4], h[5], h[6], h[7]);
    } else {
      const float4* hp = (const float4*)(hi + (size_t)node * 128 + l16 * 8);
      float4 a = hp[0], b = hp[1];
      float h[8] = {a.x, a.y, a.z, a.w, b.x, b.y, b.z, b.w};
      #pragma unroll
      for (int i = 0; i < 8; i++) h[i] += 0.2f * nw[i];
      ((uint4*)ahi)[(size_t)node * 16 + l16] = pack8(h);
    }
  }
}

// ---------------- fused final GEMM via MFMA bf16 ------------------------------
// out = lrelu([ein | ahi | x] @ Wall + lin_b) + x0
// B (fragment-ordered wfr, 96KB) staged through DOUBLE-BUFFERED LDS in four
// 24KB chunks. Linear coalesced staging; lane-contiguous LDS reads (0 bank
// conflicts); T14 async split: next chunk's loads in flight across the MFMAs;
// one barrier per chunk.
__global__ __launch_bounds__(256)
void k_gemm2(const float* __restrict__ ein, const unsigned short* __restrict__ ahi,
             const float* __restrict__ x, const unsigned short* __restrict__ wfr,
             const float* __restrict__ lin_b, const float* __restrict__ x0,
             float* __restrict__ out) {
  __shared__ __align__(16) unsigned short Bs[2][24 * 512];
  int tid = threadIdx.x;
  int lane = tid & 63, wv = tid >> 6;
  int quad = lane >> 4, l16 = lane & 15;
  int n0 = blockIdx.x * 64;
  int rA = n0 + wv * 16 + l16;
  if (rA >= N_NODES) rA = N_NODES - 1;      // clamped dup; store-guarded
  int kq = quad * 8;

  // ---- 12 a_frags in registers (A row = rA) ----
  short8 af[12];
  #pragma unroll
  for (int kb = 0; kb < 4; kb++) {          // cols 0-127: ein (fp32 -> bf16)
    const float4* p = (const float4*)(ein + (size_t)rA * 128 + kb * 32 + kq);
    float4 a = p[0], b = p[1];
    short8 t;
    t[0] = (short)f2bf(a.x); t[1] = (short)f2bf(a.y);
    t[2] = (short)f2bf(a.z); t[3] = (short)f2bf(a.w);
    t[4] = (short)f2bf(b.x); t[5] = (short)f2bf(b.y);
    t[6] = (short)f2bf(b.z); t[7] = (short)f2bf(b.w);
    af[kb] = t;
  }
  #pragma unroll
  for (int kb = 0; kb < 4; kb++)            // cols 128-255: ahi (bf16)
    af[4 + kb] = *(const short8*)(ahi + (size_t)rA * 128 + kb * 32 + kq);
  #pragma unroll
  for (int kb = 0; kb < 4; kb++) {          // cols 256-383: x (fp32 -> bf16)
    const float4* p = (const float4*)(x + (size_t)rA * 128 + kb * 32 + kq);
    float4 a = p[0], b = p[1];
    short8 t;
    t[0] = (short)f2bf(a.x); t[1] = (short)f2bf(a.y);
    t[2] = (short)f2bf(a.z); t[3] = (short)f2bf(a.w);
    t[4] = (short)f2bf(b.x); t[5] = (short)f2bf(b.y);
    t[6] = (short)f2bf(b.z); t[7] = (short)f2bf(b.w);
    af[8 + kb] = t;
  }

  f32x4 acc[8];
  #pragma unroll
  for (int i = 0; i < 8; i++) acc[i] = (f32x4){0.f, 0.f, 0.f, 0.f};

  const uint4* W4 = (const uint4*)wfr;      // 6144 uint4 total, 1536/chunk

  // ---- prologue: stage chunk 0 ----
  {
    uint4 tmp[6];
    #pragma unroll
    for (int i = 0; i < 6; i++) tmp[i] = W4[tid + i * 256];
    uint4* B4 = (uint4*)Bs[0];
    #pragma unroll
    for (int i = 0; i < 6; i++) B4[tid + i * 256] = tmp[i];
  }
  __syncthreads();

  #pragma unroll
  for (int ch = 0; ch < 4; ch++) {
    int cur = ch & 1;
    // issue next chunk's global loads (in flight across the MFMAs below)
    uint4 tmp[6];
    if (ch < 3) {
      #pragma unroll
      for (int i = 0; i < 6; i++) tmp[i] = W4[(ch + 1) * 1536 + tid + i * 256];
    }
    // compute on current chunk: 2 col-tiles x 12 kb
    const unsigned short* Bc = Bs[cur];
    #pragma unroll
    for (int ctl = 0; ctl < 2; ctl++) {
      #pragma unroll
      for (int kb = 0; kb < 12; kb++) {
        short8 b = *(const short8*)(Bc + (ctl * 12 + kb) * 512 + (lane << 3));
        acc[ch * 2 + ctl] =
            __builtin_amdgcn_mfma_f32_16x16x32_bf16(af[kb], b, acc[ch * 2 + ctl], 0, 0, 0);
      }
    }
    // write next chunk and publish with a single barrier
    if (ch < 3) {
      uint4* B4 = (uint4*)Bs[cur ^ 1];
      #pragma unroll
      for (int i = 0; i < 6; i++) B4[tid + i * 256] = tmp[i];
      __syncthreads();
    }
  }

  // ---- epilogue: +bias, lrelu, +x0 ----
  #pragma unroll
  for (int ct = 0; ct < 8; ct++) {
    int col = ct * 16 + l16;
    float bl = lin_b[col];
    #pragma unroll
    for (int r = 0; r < 4; r++) {
      int gn = n0 + wv * 16 + quad * 4 + r;
      if (gn < N_NODES) {
        float v = acc[ct][r] + bl;
        v = (v > 0.f) ? v : 0.01f * v;
        out[(size_t)gn * 128 + col] = v + x0[(size_t)gn * 128 + col];
      }
    }
  }
}

extern "C" void kernel_launch(void* const* d_in, const int* in_sizes, int n_in,
                              void* d_out, int out_size, void* d_ws, size_t ws_size,
                              hipStream_t stream) {
  const int*   src     = (const int*)d_in[0];
  const int*   dst     = (const int*)d_in[1];
  const float* x0      = (const float*)d_in[2];
  const float* x       = (const float*)d_in[3];
  const float* ein     = (const float*)d_in[4];
  const float* alpha   = (const float*)d_in[7];
  const float* emb     = (const float*)d_in[8];
  const float* w1      = (const float*)d_in[9];
  const float* b1      = (const float*)d_in[10];
  const float* w2      = (const float*)d_in[11];
  const float* b2      = (const float*)d_in[12];
  const float* weights = (const float*)d_in[13];
  const float* lin_w   = (const float*)d_in[14];
  const float* lin_b   = (const float*)d_in[15];
  float* out = (float*)d_out;

  // workspace layout (~82 MB)
  unsigned short* xk_bf  = (unsigned short*)d_ws;             // N*128 bf16
  unsigned short* xk1_bf = xk_bf  + (size_t)N_NODES * 128;
  unsigned short* ahi    = xk1_bf + (size_t)N_NODES * 128;
  unsigned short* wfr    = ahi    + (size_t)N_NODES * 128;    // 96*512 bf16 frag-order
  float* dinv = (float*)(wfr + 128 * 392);
  int* degs   = (int*)(dinv + N_NODES);
  int* offs   = degs + N_NODES;
  int* cursor = offs + N_NODES;
  int* aux    = cursor + N_NODES;
  int* aux2   = aux + 512;
  int* csr    = aux2 + 512;

  hipMemsetAsync(degs, 0, sizeof(int) * 3 * (size_t)N_NODES, stream);

  int gN = (N_NODES + 255) / 256;   // 391
  int gE = (N_EDGES + 255) / 256;

  // fused: MLP + degree count + weight precompute (independent work, 1 dispatch)
  k_front<<<G_MLP + G_DEG + G_PRE, 256, 0, stream>>>(
      x, w1, w2, b1, b2, emb, alpha, xk_bf, dst, degs, weights, lin_w, wfr);

  k_scan1<<<gN, 256, 0, stream>>>(degs, offs, aux);
  k_scan2<<<1, 512, 0, stream>>>(aux, aux2, gN);
  k_scan3<<<gN, 256, 0, stream>>>(offs, aux2, degs, dinv);
  k_fill <<<gE, 256, 0, stream>>>(src, dst, offs, cursor, csr);

  float* hi = out;   // fp32 hi lives in d_out between pass1 and gemm
  k_gather<1><<<N_NODES / 4, 256, 0, stream>>>(xk_bf,  xk1_bf, hi, nullptr, csr, offs, degs, dinv);
  k_gather<2><<<N_NODES / 4, 256, 0, stream>>>(xk1_bf, nullptr, hi, ahi,    csr, offs, degs, dinv);

  k_gemm2<<<(N_NODES + 63) / 64, 256, 0, stream>>>(ein, ahi, x, wfr, lin_b, x0, out);
}

// Round 8
// 424.917 us; speedup vs baseline: 1.1541x; 1.0241x over previous
//
#include <hip/hip_runtime.h>

#define N_NODES 100000
#define N_EDGES 800000
#define D 128

// grid split for the fused front kernel
#define G_MLP 782             // (N_NODES+127)/128
#define G_DEG 3125            // (N_EDGES+255)/256
#define G_PRE 192             // 384*128/256

typedef __attribute__((ext_vector_type(8))) short short8;
typedef __attribute__((ext_vector_type(4))) float f32x4;

__device__ inline unsigned short f2bf(float f) {
  unsigned u = __float_as_uint(f);
  unsigned r = (u + 0x7fffu + ((u >> 16) & 1u)) >> 16;
  return (unsigned short)r;
}
__device__ inline void bfma8(float* acc, const uint4 v, float d) {
  acc[0] = fmaf(__uint_as_float(v.x << 16), d, acc[0]);
  acc[1] = fmaf(__uint_as_float(v.x & 0xffff0000u), d, acc[1]);
  acc[2] = fmaf(__uint_as_float(v.y << 16), d, acc[2]);
  acc[3] = fmaf(__uint_as_float(v.y & 0xffff0000u), d, acc[3]);
  acc[4] = fmaf(__uint_as_float(v.z << 16), d, acc[4]);
  acc[5] = fmaf(__uint_as_float(v.z & 0xffff0000u), d, acc[5]);
  acc[6] = fmaf(__uint_as_float(v.w << 16), d, acc[6]);
  acc[7] = fmaf(__uint_as_float(v.w & 0xffff0000u), d, acc[7]);
}
__device__ inline void unpack8(float* o, const uint4 v) {
  o[0] = __uint_as_float(v.x << 16); o[1] = __uint_as_float(v.x & 0xffff0000u);
  o[2] = __uint_as_float(v.y << 16); o[3] = __uint_as_float(v.y & 0xffff0000u);
  o[4] = __uint_as_float(v.z << 16); o[5] = __uint_as_float(v.z & 0xffff0000u);
  o[6] = __uint_as_float(v.w << 16); o[7] = __uint_as_float(v.w & 0xffff0000u);
}
__device__ inline uint4 pack8(const float* v) {
  uint4 r;
  r.x = (unsigned)f2bf(v[0]) | ((unsigned)f2bf(v[1]) << 16);
  r.y = (unsigned)f2bf(v[2]) | ((unsigned)f2bf(v[3]) << 16);
  r.z = (unsigned)f2bf(v[4]) | ((unsigned)f2bf(v[5]) << 16);
  r.w = (unsigned)f2bf(v[6]) | ((unsigned)f2bf(v[7]) << 16);
  return r;
}

// ---------------- fused front: MLP (blocks 0..G_MLP) + degree count + wfr ----
// MLP: 128 nodes/block, acc[8 nodes][8 dims]/thread, swizzled w1sT (2-way free).
__global__ __launch_bounds__(256, 4)
void k_front(const float* __restrict__ x, const float* __restrict__ w1,
             const float* __restrict__ w2, const float* __restrict__ b1,
             const float* __restrict__ b2, const float* __restrict__ emb,
             const float* __restrict__ alpha_p, unsigned short* __restrict__ xk_bf,
             const int* __restrict__ dst, int* __restrict__ degs,
             const float* __restrict__ weights, const float* __restrict__ lin_w,
             unsigned short* __restrict__ wfr) {
  int tid = threadIdx.x;
  int bid = blockIdx.x;

  if (bid >= G_MLP) {
    if (bid < G_MLP + G_DEG) {
      // ---- degree count ----
      int e = (bid - G_MLP) * 256 + tid;
      if (e < N_EDGES) atomicAdd(&degs[dst[e]], 1);
    } else {
      // ---- precompute merged weights -> bf16, MFMA-FRAGMENT order ----
      int gid = (bid - G_MLP - G_DEG) * 256 + tid;   // 384*128 threads
      int k = gid >> 7, d = gid & 127;
      float v;
      if (k < 128) {
        v = lin_w[d * 256 + k];
      } else {
        const float* wrow = weights + (k - 128) * 128;
        const float* lcol = lin_w + d * 256 + 128;
        float s = 0.f;
        for (int j = 0; j < 128; j++) s += wrow[j] * lcol[j];
        v = s;
      }
      int ct = d >> 4, kb = k >> 5;
      int lane = (((k >> 3) & 3) << 4) | (d & 15);
      int j = k & 7;
      wfr[((ct * 12 + kb) << 9) + (lane << 3) + j] = f2bf(v);
    }
    return;
  }

  // ---- per-node MLP -> prob -> xk(bf16), 128 nodes/block ----
  __shared__ __align__(16) float w1sT[32 * 140];   // swizzled: dim j at j+(j>>5)*4
  __shared__ __align__(16) float xsT[32 * 132];    // [k][node]
  __shared__ float zbuf[128];
  __shared__ float pbuf[128];

  int n0 = bid * 128;
  int d8 = tid & 15;        // 8-dim group
  int n8 = tid >> 4;        // 8-node group
  int woff = d8 * 8 + ((d8 >> 2) << 2);   // swizzled read offset into w1sT row

  float acc[8][8];
  #pragma unroll
  for (int a = 0; a < 8; a++)
    #pragma unroll
    for (int c = 0; c < 8; c++) acc[a][c] = 0.f;

  for (int p = 0; p < 4; p++) {
    __syncthreads();
    {  // stage w1 K-slice, transposed+swizzled: w1sT[k][off(j)]
      int j = tid >> 1;
      int kg0 = (tid & 1) * 4;
      int offj = j + ((j >> 5) << 2);
      const float4* wr = (const float4*)(w1 + j * 128 + p * 32);
      #pragma unroll
      for (int c = 0; c < 4; c++) {
        float4 v = wr[kg0 + c];
        int k = (kg0 + c) * 4;
        w1sT[(k + 0) * 140 + offj] = v.x;
        w1sT[(k + 1) * 140 + offj] = v.y;
        w1sT[(k + 2) * 140 + offj] = v.z;
        w1sT[(k + 3) * 140 + offj] = v.w;
      }
    }
    {  // stage x K-slice, transposed: xsT[k][n], 128 nodes x 32 k
      int n = tid & 127;
      int kh = tid >> 7;          // 0/1: which 16-k half
      int gn = n0 + n;
      const float4* xr = (const float4*)(x + (size_t)gn * 128 + p * 32 + kh * 16);
      #pragma unroll
      for (int i = 0; i < 4; i++) {
        float4 v = make_float4(0.f, 0.f, 0.f, 0.f);
        if (gn < N_NODES) v = xr[i];
        int k = kh * 16 + i * 4;
        xsT[(k + 0) * 132 + n] = v.x;
        xsT[(k + 1) * 132 + n] = v.y;
        xsT[(k + 2) * 132 + n] = v.z;
        xsT[(k + 3) * 132 + n] = v.w;
      }
    }
    __syncthreads();

    #pragma unroll 4
    for (int kk = 0; kk < 32; kk++) {
      const float4* wp = (const float4*)(w1sT + kk * 140 + woff);
      float4 wa = wp[0], wb = wp[1];
      const float4* fp = (const float4*)(xsT + kk * 132 + n8 * 8);
      float4 fa = fp[0], fb = fp[1];
      float w[8] = {wa.x, wa.y, wa.z, wa.w, wb.x, wb.y, wb.z, wb.w};
      float f[8] = {fa.x, fa.y, fa.z, fa.w, fb.x, fb.y, fb.z, fb.w};
      #pragma unroll
      for (int a = 0; a < 8; a++)
        #pragma unroll
        for (int c = 0; c < 8; c++)
          acc[a][c] = fmaf(f[a], w[c], acc[a][c]);
    }
  }

  {
    int j0 = d8 * 8;
    float bb[8], wd[8];
    #pragma unroll
    for (int c = 0; c < 8; c++) {
      bb[c] = b1[j0 + c];
      wd[c] = w2[128 + j0 + c] - w2[j0 + c];
    }
    #pragma unroll
    for (int a = 0; a < 8; a++) {
      float s = 0.f;
      #pragma unroll
      for (int c = 0; c < 8; c++) {
        float h = fmaxf(acc[a][c] + bb[c], 0.f);
        s += h * wd[c];
      }
      s += __shfl_down(s, 8);
      s += __shfl_down(s, 4);
      s += __shfl_down(s, 2);
      s += __shfl_down(s, 1);
      if (d8 == 0) zbuf[n8 * 8 + a] = s;
    }
  }
  __syncthreads();
  if (tid < 128) {
    float db2 = b2[1] - b2[0];
    float z = zbuf[tid] + db2;
    pbuf[tid] = 1.f / (1.f + expf(-z));
  }
  __syncthreads();

  {
    float al = alpha_p[0];
    int d4 = tid & 31;
    const float4 e0 = ((const float4*)emb)[d4];
    const float4 e1 = ((const float4*)(emb + 128))[d4];
    #pragma unroll
    for (int i = 0; i < 16; i++) {
      int n = i * 8 + (tid >> 5);
      int gn = n0 + n;
      if (gn >= N_NODES) continue;
      float p = pbuf[n];
      float c0 = al * (1.f - p), c1 = al * p;
      float4 xv = ((const float4*)x)[(size_t)gn * 32 + d4];
      float o0 = xv.x + c0 * e0.x + c1 * e1.x;
      float o1 = xv.y + c0 * e0.y + c1 * e1.y;
      float o2 = xv.z + c0 * e0.z + c1 * e1.z;
      float o3 = xv.w + c0 * e0.w + c1 * e1.w;
      ushort4 ov = make_ushort4(f2bf(o0), f2bf(o1), f2bf(o2), f2bf(o3));
      ((ushort4*)xk_bf)[(size_t)gn * 32 + d4] = ov;
    }
  }
}

// ---------------- 2-level exclusive scan over degrees ----------------
__global__ void k_scan1(const int* __restrict__ degs, int* __restrict__ offs,
                        int* __restrict__ aux) {
  __shared__ int s[256];
  int tid = threadIdx.x;
  int i = blockIdx.x * 256 + tid;
  int v = (i < N_NODES) ? degs[i] : 0;
  int sum = v;
  s[tid] = sum; __syncthreads();
  for (int off = 1; off < 256; off <<= 1) {
    int t = (tid >= off) ? s[tid - off] : 0;
    __syncthreads();
    sum += t; s[tid] = sum;
    __syncthreads();
  }
  if (i < N_NODES) offs[i] = sum - v;
  if (tid == 255) aux[blockIdx.x] = sum;
}

__global__ void k_scan2(const int* __restrict__ aux, int* __restrict__ aux2, int nblk) {
  __shared__ int s[512];
  int tid = threadIdx.x;
  int v = (tid < nblk) ? aux[tid] : 0;
  int sum = v;
  s[tid] = sum; __syncthreads();
  for (int off = 1; off < 512; off <<= 1) {
    int t = (tid >= off) ? s[tid - off] : 0;
    __syncthreads();
    sum += t; s[tid] = sum;
    __syncthreads();
  }
  aux2[tid] = sum - v;
}

__global__ void k_scan3(int* __restrict__ offs, const int* __restrict__ aux2,
                        const int* __restrict__ degs, float* __restrict__ dinv) {
  int i = blockIdx.x * 256 + threadIdx.x;
  if (i < N_NODES) {
    offs[i] += aux2[blockIdx.x];
    dinv[i] = rsqrtf(fmaxf((float)degs[i], 1.0f));
  }
}

// ---------------- CSR fill (counting sort by dst) ----------------
__global__ void k_fill(const int* __restrict__ src, const int* __restrict__ dst,
                       const int* __restrict__ offs, int* __restrict__ cursor,
                       int* __restrict__ csr) {
  int e = blockIdx.x * 256 + threadIdx.x;
  if (e < N_EDGES) {
    int d = dst[e];
    int pos = offs[d] + atomicAdd(&cursor[d], 1);
    csr[pos] = src[e];
  }
}

// ---------------- Laplacian gather passes, bf16 feat, 4 edges/instr ----------
template <int PASS>
__global__ __launch_bounds__(256)
void k_gather(const unsigned short* __restrict__ feat,
              unsigned short* __restrict__ feat_out,
              float* __restrict__ hi,
              unsigned short* __restrict__ ahi,
              const int* __restrict__ csr, const int* __restrict__ offs,
              const int* __restrict__ degs, const float* __restrict__ dinv) {
  int node = blockIdx.x * 4 + (threadIdx.x >> 6);
  int lane = threadIdx.x & 63;
  int quad = lane >> 4;
  int l16 = lane & 15;
  int start = offs[node];
  int cnt = degs[node];
  const uint4* f16 = (const uint4*)feat;   // one row = 16 uint4
  float acc[8];
  #pragma unroll
  for (int i = 0; i < 8; i++) acc[i] = 0.f;

  int j = 0;
  for (; j + 8 <= cnt; j += 8) {            // 8 edges in flight
    int sa = csr[start + j + quad];
    int sb = csr[start + j + 4 + quad];
    float da = dinv[sa], db = dinv[sb];
    uint4 va = f16[(size_t)sa * 16 + l16];
    uint4 vb = f16[(size_t)sb * 16 + l16];
    bfma8(acc, va, da);
    bfma8(acc, vb, db);
  }
  if (j + 4 <= cnt) {
    int s = csr[start + j + quad];
    float d = dinv[s];
    uint4 v = f16[(size_t)s * 16 + l16];
    bfma8(acc, v, d);
    j += 4;
  }
  int rem = cnt - j;                        // 0..3
  if (quad < rem) {
    int s = csr[start + j + quad];
    float d = dinv[s];
    uint4 v = f16[(size_t)s * 16 + l16];
    bfma8(acc, v, d);
  }

  #pragma unroll
  for (int i = 0; i < 8; i++) {
    acc[i] += __shfl_down(acc[i], 32);
    acc[i] += __shfl_down(acc[i], 16);
  }

  if (quad == 0) {
    float dvi = dinv[node];
    float old[8], nw[8];
    unpack8(old, f16[(size_t)node * 16 + l16]);
    #pragma unroll
    for (int i = 0; i < 8; i++) nw[i] = old[i] - acc[i] * dvi;
    if (PASS == 1) {
      ((uint4*)feat_out)[(size_t)node * 16 + l16] = pack8(nw);
      float h[8];
      #pragma unroll
      for (int i = 0; i < 8; i++) h[i] = 0.5f * old[i] + 0.3f * nw[i];
      float4* hp = (float4*)(hi + (size_t)node * 128 + l16 * 8);
      hp[0] = make_float4(h[0], h[1], h[2], h[3]);
      hp[1] = make_float4(h[4], h[5], h[6], h[7]);
    } else {
      const float4* hp = (const float4*)(hi + (size_t)node * 128 + l16 * 8);
      float4 a = hp[0], b = hp[1];
      float h[8] = {a.x, a.y, a.z, a.w, b.x, b.y, b.z, b.w};
      #pragma unroll
      for (int i = 0; i < 8; i++) h[i] += 0.2f * nw[i];
      ((uint4*)ahi)[(size_t)node * 16 + l16] = pack8(h);
    }
  }
}

// ---------------- fused final GEMM via MFMA bf16 ------------------------------
// out = lrelu([ein | ahi | x] @ Wall + lin_b) + x0
// 512 threads / 128 rows per block (8 waves). Per-wave work identical to the
// 256-thread version; the change is WAVE RESIDENCY: LDS 48KB -> 3 blocks/CU =
// 24 waves/CU cap (vs 12). Three prior structures all sat at ~85us with ~8
// waves/CU and every pipe <25% -> latency-bound on concurrency, so double the
// independent load streams per CU. Frag-ordered B, dbuf LDS, 1 barrier/chunk.
__global__ __launch_bounds__(512)
void k_gemm2(const float* __restrict__ ein, const unsigned short* __restrict__ ahi,
             const float* __restrict__ x, const unsigned short* __restrict__ wfr,
             const float* __restrict__ lin_b, const float* __restrict__ x0,
             float* __restrict__ out) {
  __shared__ __align__(16) unsigned short Bs[2][24 * 512];
  int tid = threadIdx.x;
  int lane = tid & 63, wv = tid >> 6;          // 8 waves
  int quad = lane >> 4, l16 = lane & 15;
  int n0 = blockIdx.x * 128;
  int rA = n0 + wv * 16 + l16;
  if (rA >= N_NODES) rA = N_NODES - 1;      // clamped dup; store-guarded
  int kq = quad * 8;

  // ---- 12 a_frags in registers (A row = rA) ----
  short8 af[12];
  #pragma unroll
  for (int kb = 0; kb < 4; kb++) {          // cols 0-127: ein (fp32 -> bf16)
    const float4* p = (const float4*)(ein + (size_t)rA * 128 + kb * 32 + kq);
    float4 a = p[0], b = p[1];
    short8 t;
    t[0] = (short)f2bf(a.x); t[1] = (short)f2bf(a.y);
    t[2] = (short)f2bf(a.z); t[3] = (short)f2bf(a.w);
    t[4] = (short)f2bf(b.x); t[5] = (short)f2bf(b.y);
    t[6] = (short)f2bf(b.z); t[7] = (short)f2bf(b.w);
    af[kb] = t;
  }
  #pragma unroll
  for (int kb = 0; kb < 4; kb++)            // cols 128-255: ahi (bf16)
    af[4 + kb] = *(const short8*)(ahi + (size_t)rA * 128 + kb * 32 + kq);
  #pragma unroll
  for (int kb = 0; kb < 4; kb++) {          // cols 256-383: x (fp32 -> bf16)
    const float4* p = (const float4*)(x + (size_t)rA * 128 + kb * 32 + kq);
    float4 a = p[0], b = p[1];
    short8 t;
    t[0] = (short)f2bf(a.x); t[1] = (short)f2bf(a.y);
    t[2] = (short)f2bf(a.z); t[3] = (short)f2bf(a.w);
    t[4] = (short)f2bf(b.x); t[5] = (short)f2bf(b.y);
    t[6] = (short)f2bf(b.z); t[7] = (short)f2bf(b.w);
    af[8 + kb] = t;
  }

  f32x4 acc[8];
  #pragma unroll
  for (int i = 0; i < 8; i++) acc[i] = (f32x4){0.f, 0.f, 0.f, 0.f};

  const uint4* W4 = (const uint4*)wfr;      // 6144 uint4 total, 1536/chunk

  // ---- prologue: stage chunk 0 (512 threads x 3 uint4) ----
  {
    uint4 tmp[3];
    #pragma unroll
    for (int i = 0; i < 3; i++) tmp[i] = W4[tid + i * 512];
    uint4* B4 = (uint4*)Bs[0];
    #pragma unroll
    for (int i = 0; i < 3; i++) B4[tid + i * 512] = tmp[i];
  }
  __syncthreads();

  #pragma unroll
  for (int ch = 0; ch < 4; ch++) {
    int cur = ch & 1;
    // issue next chunk's global loads (in flight across the MFMAs below)
    uint4 tmp[3];
    if (ch < 3) {
      #pragma unroll
      for (int i = 0; i < 3; i++) tmp[i] = W4[(ch + 1) * 1536 + tid + i * 512];
    }
    // compute on current chunk: 2 col-tiles x 12 kb
    const unsigned short* Bc = Bs[cur];
    #pragma unroll
    for (int ctl = 0; ctl < 2; ctl++) {
      #pragma unroll
      for (int kb = 0; kb < 12; kb++) {
        short8 b = *(const short8*)(Bc + (ctl * 12 + kb) * 512 + (lane << 3));
        acc[ch * 2 + ctl] =
            __builtin_amdgcn_mfma_f32_16x16x32_bf16(af[kb], b, acc[ch * 2 + ctl], 0, 0, 0);
      }
    }
    // write next chunk and publish with a single barrier
    if (ch < 3) {
      uint4* B4 = (uint4*)Bs[cur ^ 1];
      #pragma unroll
      for (int i = 0; i < 3; i++) B4[tid + i * 512] = tmp[i];
      __syncthreads();
    }
  }

  // ---- epilogue: +bias, lrelu, +x0 ----
  #pragma unroll
  for (int ct = 0; ct < 8; ct++) {
    int col = ct * 16 + l16;
    float bl = lin_b[col];
    #pragma unroll
    for (int r = 0; r < 4; r++) {
      int gn = n0 + wv * 16 + quad * 4 + r;
      if (gn < N_NODES) {
        float v = acc[ct][r] + bl;
        v = (v > 0.f) ? v : 0.01f * v;
        out[(size_t)gn * 128 + col] = v + x0[(size_t)gn * 128 + col];
      }
    }
  }
}

extern "C" void kernel_launch(void* const* d_in, const int* in_sizes, int n_in,
                              void* d_out, int out_size, void* d_ws, size_t ws_size,
                              hipStream_t stream) {
  const int*   src     = (const int*)d_in[0];
  const int*   dst     = (const int*)d_in[1];
  const float* x0      = (const float*)d_in[2];
  const float* x       = (const float*)d_in[3];
  const float* ein     = (const float*)d_in[4];
  const float* alpha   = (const float*)d_in[7];
  const float* emb     = (const float*)d_in[8];
  const float* w1      = (const float*)d_in[9];
  const float* b1      = (const float*)d_in[10];
  const float* w2      = (const float*)d_in[11];
  const float* b2      = (const float*)d_in[12];
  const float* weights = (const float*)d_in[13];
  const float* lin_w   = (const float*)d_in[14];
  const float* lin_b   = (const float*)d_in[15];
  float* out = (float*)d_out;

  // workspace layout (~82 MB)
  unsigned short* xk_bf  = (unsigned short*)d_ws;             // N*128 bf16
  unsigned short* xk1_bf = xk_bf  + (size_t)N_NODES * 128;
  unsigned short* ahi    = xk1_bf + (size_t)N_NODES * 128;
  unsigned short* wfr    = ahi    + (size_t)N_NODES * 128;    // 96*512 bf16 frag-order
  float* dinv = (float*)(wfr + 128 * 392);
  int* degs   = (int*)(dinv + N_NODES);
  int* offs   = degs + N_NODES;
  int* cursor = offs + N_NODES;
  int* aux    = cursor + N_NODES;
  int* aux2   = aux + 512;
  int* csr    = aux2 + 512;

  hipMemsetAsync(degs, 0, sizeof(int) * 3 * (size_t)N_NODES, stream);

  int gN = (N_NODES + 255) / 256;   // 391
  int gE = (N_EDGES + 255) / 256;

  // fused: MLP + degree count + weight precompute (independent work, 1 dispatch)
  k_front<<<G_MLP + G_DEG + G_PRE, 256, 0, stream>>>(
      x, w1, w2, b1, b2, emb, alpha, xk_bf, dst, degs, weights, lin_w, wfr);

  k_scan1<<<gN, 256, 0, stream>>>(degs, offs, aux);
  k_scan2<<<1, 512, 0, stream>>>(aux, aux2, gN);
  k_scan3<<<gN, 256, 0, stream>>>(offs, aux2, degs, dinv);
  k_fill <<<gE, 256, 0, stream>>>(src, dst, offs, cursor, csr);

  float* hi = out;   // fp32 hi lives in d_out between pass1 and gemm
  k_gather<1><<<N_NODES / 4, 256, 0, stream>>>(xk_bf,  xk1_bf, hi, nullptr, csr, offs, degs, dinv);
  k_gather<2><<<N_NODES / 4, 256, 0, stream>>>(xk1_bf, nullptr, hi, ahi,    csr, offs, degs, dinv);

  k_gemm2<<<(N_NODES + 127) / 128, 512, 0, stream>>>(ein, ahi, x, wfr, lin_b, x0, out);
}

// Round 9
// 411.050 us; speedup vs baseline: 1.1930x; 1.0337x over previous
//
#include <hip/hip_runtime.h>

#define N_NODES 100000
#define N_EDGES 800000
#define D 128

// grid split for the fused front kernel
#define G_MLP 782             // (N_NODES+127)/128
#define G_DEG 3125            // (N_EDGES+255)/256
#define G_PRE 192             // 384*128/256

typedef __attribute__((ext_vector_type(8))) short short8;
typedef __attribute__((ext_vector_type(4))) float f32x4;

__device__ inline unsigned short f2bf(float f) {
  unsigned u = __float_as_uint(f);
  unsigned r = (u + 0x7fffu + ((u >> 16) & 1u)) >> 16;
  return (unsigned short)r;
}
__device__ inline void bfma8(float* acc, const uint4 v, float d) {
  acc[0] = fmaf(__uint_as_float(v.x << 16), d, acc[0]);
  acc[1] = fmaf(__uint_as_float(v.x & 0xffff0000u), d, acc[1]);
  acc[2] = fmaf(__uint_as_float(v.y << 16), d, acc[2]);
  acc[3] = fmaf(__uint_as_float(v.y & 0xffff0000u), d, acc[3]);
  acc[4] = fmaf(__uint_as_float(v.z << 16), d, acc[4]);
  acc[5] = fmaf(__uint_as_float(v.z & 0xffff0000u), d, acc[5]);
  acc[6] = fmaf(__uint_as_float(v.w << 16), d, acc[6]);
  acc[7] = fmaf(__uint_as_float(v.w & 0xffff0000u), d, acc[7]);
}
__device__ inline void unpack8(float* o, const uint4 v) {
  o[0] = __uint_as_float(v.x << 16); o[1] = __uint_as_float(v.x & 0xffff0000u);
  o[2] = __uint_as_float(v.y << 16); o[3] = __uint_as_float(v.y & 0xffff0000u);
  o[4] = __uint_as_float(v.z << 16); o[5] = __uint_as_float(v.z & 0xffff0000u);
  o[6] = __uint_as_float(v.w << 16); o[7] = __uint_as_float(v.w & 0xffff0000u);
}
__device__ inline uint4 pack8(const float* v) {
  uint4 r;
  r.x = (unsigned)f2bf(v[0]) | ((unsigned)f2bf(v[1]) << 16);
  r.y = (unsigned)f2bf(v[2]) | ((unsigned)f2bf(v[3]) << 16);
  r.z = (unsigned)f2bf(v[4]) | ((unsigned)f2bf(v[5]) << 16);
  r.w = (unsigned)f2bf(v[6]) | ((unsigned)f2bf(v[7]) << 16);
  return r;
}

// ---------------- fused front: MLP (blocks 0..G_MLP) + degree count + wfr ----
// MLP: 128 nodes/block, acc[8 nodes][8 dims]/thread, swizzled w1sT (2-way free).
__global__ __launch_bounds__(256, 4)
void k_front(const float* __restrict__ x, const float* __restrict__ w1,
             const float* __restrict__ w2, const float* __restrict__ b1,
             const float* __restrict__ b2, const float* __restrict__ emb,
             const float* __restrict__ alpha_p, unsigned short* __restrict__ xk_bf,
             const int* __restrict__ dst, int* __restrict__ degs,
             const float* __restrict__ weights, const float* __restrict__ lin_w,
             unsigned short* __restrict__ wfr) {
  int tid = threadIdx.x;
  int bid = blockIdx.x;

  if (bid >= G_MLP) {
    if (bid < G_MLP + G_DEG) {
      // ---- degree count ----
      int e = (bid - G_MLP) * 256 + tid;
      if (e < N_EDGES) atomicAdd(&degs[dst[e]], 1);
    } else {
      // ---- precompute merged weights -> bf16, MFMA-FRAGMENT order ----
      int gid = (bid - G_MLP - G_DEG) * 256 + tid;   // 384*128 threads
      int k = gid >> 7, d = gid & 127;
      float v;
      if (k < 128) {
        v = lin_w[d * 256 + k];
      } else {
        const float* wrow = weights + (k - 128) * 128;
        const float* lcol = lin_w + d * 256 + 128;
        float s = 0.f;
        for (int j = 0; j < 128; j++) s += wrow[j] * lcol[j];
        v = s;
      }
      int ct = d >> 4, kb = k >> 5;
      int lane = (((k >> 3) & 3) << 4) | (d & 15);
      int j = k & 7;
      wfr[((ct * 12 + kb) << 9) + (lane << 3) + j] = f2bf(v);
    }
    return;
  }

  // ---- per-node MLP -> prob -> xk(bf16), 128 nodes/block ----
  __shared__ __align__(16) float w1sT[32 * 140];   // swizzled: dim j at j+(j>>5)*4
  __shared__ __align__(16) float xsT[32 * 132];    // [k][node]
  __shared__ float zbuf[128];
  __shared__ float pbuf[128];

  int n0 = bid * 128;
  int d8 = tid & 15;        // 8-dim group
  int n8 = tid >> 4;        // 8-node group
  int woff = d8 * 8 + ((d8 >> 2) << 2);   // swizzled read offset into w1sT row

  float acc[8][8];
  #pragma unroll
  for (int a = 0; a < 8; a++)
    #pragma unroll
    for (int c = 0; c < 8; c++) acc[a][c] = 0.f;

  for (int p = 0; p < 4; p++) {
    __syncthreads();
    {  // stage w1 K-slice, transposed+swizzled: w1sT[k][off(j)]
      int j = tid >> 1;
      int kg0 = (tid & 1) * 4;
      int offj = j + ((j >> 5) << 2);
      const float4* wr = (const float4*)(w1 + j * 128 + p * 32);
      #pragma unroll
      for (int c = 0; c < 4; c++) {
        float4 v = wr[kg0 + c];
        int k = (kg0 + c) * 4;
        w1sT[(k + 0) * 140 + offj] = v.x;
        w1sT[(k + 1) * 140 + offj] = v.y;
        w1sT[(k + 2) * 140 + offj] = v.z;
        w1sT[(k + 3) * 140 + offj] = v.w;
      }
    }
    {  // stage x K-slice, transposed: xsT[k][n], 128 nodes x 32 k
      int n = tid & 127;
      int kh = tid >> 7;          // 0/1: which 16-k half
      int gn = n0 + n;
      const float4* xr = (const float4*)(x + (size_t)gn * 128 + p * 32 + kh * 16);
      #pragma unroll
      for (int i = 0; i < 4; i++) {
        float4 v = make_float4(0.f, 0.f, 0.f, 0.f);
        if (gn < N_NODES) v = xr[i];
        int k = kh * 16 + i * 4;
        xsT[(k + 0) * 132 + n] = v.x;
        xsT[(k + 1) * 132 + n] = v.y;
        xsT[(k + 2) * 132 + n] = v.z;
        xsT[(k + 3) * 132 + n] = v.w;
      }
    }
    __syncthreads();

    #pragma unroll 4
    for (int kk = 0; kk < 32; kk++) {
      const float4* wp = (const float4*)(w1sT + kk * 140 + woff);
      float4 wa = wp[0], wb = wp[1];
      const float4* fp = (const float4*)(xsT + kk * 132 + n8 * 8);
      float4 fa = fp[0], fb = fp[1];
      float w[8] = {wa.x, wa.y, wa.z, wa.w, wb.x, wb.y, wb.z, wb.w};
      float f[8] = {fa.x, fa.y, fa.z, fa.w, fb.x, fb.y, fb.z, fb.w};
      #pragma unroll
      for (int a = 0; a < 8; a++)
        #pragma unroll
        for (int c = 0; c < 8; c++)
          acc[a][c] = fmaf(f[a], w[c], acc[a][c]);
    }
  }

  {
    int j0 = d8 * 8;
    float bb[8], wd[8];
    #pragma unroll
    for (int c = 0; c < 8; c++) {
      bb[c] = b1[j0 + c];
      wd[c] = w2[128 + j0 + c] - w2[j0 + c];
    }
    #pragma unroll
    for (int a = 0; a < 8; a++) {
      float s = 0.f;
      #pragma unroll
      for (int c = 0; c < 8; c++) {
        float h = fmaxf(acc[a][c] + bb[c], 0.f);
        s += h * wd[c];
      }
      s += __shfl_down(s, 8);
      s += __shfl_down(s, 4);
      s += __shfl_down(s, 2);
      s += __shfl_down(s, 1);
      if (d8 == 0) zbuf[n8 * 8 + a] = s;
    }
  }
  __syncthreads();
  if (tid < 128) {
    float db2 = b2[1] - b2[0];
    float z = zbuf[tid] + db2;
    pbuf[tid] = 1.f / (1.f + expf(-z));
  }
  __syncthreads();

  {
    float al = alpha_p[0];
    int d4 = tid & 31;
    const float4 e0 = ((const float4*)emb)[d4];
    const float4 e1 = ((const float4*)(emb + 128))[d4];
    #pragma unroll
    for (int i = 0; i < 16; i++) {
      int n = i * 8 + (tid >> 5);
      int gn = n0 + n;
      if (gn >= N_NODES) continue;
      float p = pbuf[n];
      float c0 = al * (1.f - p), c1 = al * p;
      float4 xv = ((const float4*)x)[(size_t)gn * 32 + d4];
      float o0 = xv.x + c0 * e0.x + c1 * e1.x;
      float o1 = xv.y + c0 * e0.y + c1 * e1.y;
      float o2 = xv.z + c0 * e0.z + c1 * e1.z;
      float o3 = xv.w + c0 * e0.w + c1 * e1.w;
      ushort4 ov = make_ushort4(f2bf(o0), f2bf(o1), f2bf(o2), f2bf(o3));
      ((ushort4*)xk_bf)[(size_t)gn * 32 + d4] = ov;
    }
  }
}

// ---------------- 2-level exclusive scan over degrees ----------------
__global__ void k_scan1(const int* __restrict__ degs, int* __restrict__ offs,
                        int* __restrict__ aux) {
  __shared__ int s[256];
  int tid = threadIdx.x;
  int i = blockIdx.x * 256 + tid;
  int v = (i < N_NODES) ? degs[i] : 0;
  int sum = v;
  s[tid] = sum; __syncthreads();
  for (int off = 1; off < 256; off <<= 1) {
    int t = (tid >= off) ? s[tid - off] : 0;
    __syncthreads();
    sum += t; s[tid] = sum;
    __syncthreads();
  }
  if (i < N_NODES) offs[i] = sum - v;
  if (tid == 255) aux[blockIdx.x] = sum;
}

__global__ void k_scan2(const int* __restrict__ aux, int* __restrict__ aux2, int nblk) {
  __shared__ int s[512];
  int tid = threadIdx.x;
  int v = (tid < nblk) ? aux[tid] : 0;
  int sum = v;
  s[tid] = sum; __syncthreads();
  for (int off = 1; off < 512; off <<= 1) {
    int t = (tid >= off) ? s[tid - off] : 0;
    __syncthreads();
    sum += t; s[tid] = sum;
    __syncthreads();
  }
  aux2[tid] = sum - v;
}

__global__ void k_scan3(int* __restrict__ offs, const int* __restrict__ aux2,
                        const int* __restrict__ degs, float* __restrict__ dinv) {
  int i = blockIdx.x * 256 + threadIdx.x;
  if (i < N_NODES) {
    offs[i] += aux2[blockIdx.x];
    dinv[i] = rsqrtf(fmaxf((float)degs[i], 1.0f));
  }
}

// ---------------- CSR fill (counting sort by dst) ----------------
__global__ void k_fill(const int* __restrict__ src, const int* __restrict__ dst,
                       const int* __restrict__ offs, int* __restrict__ cursor,
                       int* __restrict__ csr) {
  int e = blockIdx.x * 256 + threadIdx.x;
  if (e < N_EDGES) {
    int d = dst[e];
    int pos = offs[d] + atomicAdd(&cursor[d], 1);
    csr[pos] = src[e];
  }
}

// ---------------- Laplacian gather passes, bf16 feat, 4 edges/instr ----------
template <int PASS>
__global__ __launch_bounds__(256)
void k_gather(const unsigned short* __restrict__ feat,
              unsigned short* __restrict__ feat_out,
              float* __restrict__ hi,
              unsigned short* __restrict__ ahi,
              const int* __restrict__ csr, const int* __restrict__ offs,
              const int* __restrict__ degs, const float* __restrict__ dinv) {
  int node = blockIdx.x * 4 + (threadIdx.x >> 6);
  int lane = threadIdx.x & 63;
  int quad = lane >> 4;
  int l16 = lane & 15;
  int start = offs[node];
  int cnt = degs[node];
  const uint4* f16 = (const uint4*)feat;   // one row = 16 uint4
  float acc[8];
  #pragma unroll
  for (int i = 0; i < 8; i++) acc[i] = 0.f;

  int j = 0;
  for (; j + 8 <= cnt; j += 8) {            // 8 edges in flight
    int sa = csr[start + j + quad];
    int sb = csr[start + j + 4 + quad];
    float da = dinv[sa], db = dinv[sb];
    uint4 va = f16[(size_t)sa * 16 + l16];
    uint4 vb = f16[(size_t)sb * 16 + l16];
    bfma8(acc, va, da);
    bfma8(acc, vb, db);
  }
  if (j + 4 <= cnt) {
    int s = csr[start + j + quad];
    float d = dinv[s];
    uint4 v = f16[(size_t)s * 16 + l16];
    bfma8(acc, v, d);
    j += 4;
  }
  int rem = cnt - j;                        // 0..3
  if (quad < rem) {
    int s = csr[start + j + quad];
    float d = dinv[s];
    uint4 v = f16[(size_t)s * 16 + l16];
    bfma8(acc, v, d);
  }

  #pragma unroll
  for (int i = 0; i < 8; i++) {
    acc[i] += __shfl_down(acc[i], 32);
    acc[i] += __shfl_down(acc[i], 16);
  }

  if (quad == 0) {
    float dvi = dinv[node];
    float old[8], nw[8];
    unpack8(old, f16[(size_t)node * 16 + l16]);
    #pragma unroll
    for (int i = 0; i < 8; i++) nw[i] = old[i] - acc[i] * dvi;
    if (PASS == 1) {
      ((uint4*)feat_out)[(size_t)node * 16 + l16] = pack8(nw);
      float h[8];
      #pragma unroll
      for (int i = 0; i < 8; i++) h[i] = 0.5f * old[i] + 0.3f * nw[i];
      float4* hp = (float4*)(hi + (size_t)node * 128 + l16 * 8);
      hp[0] = make_float4(h[0], h[1], h[2], h[3]);
      hp[1] = make_float4(h[4], h[5], h[6], h[7]);
    } else {
      const float4* hp = (const float4*)(hi + (size_t)node * 128 + l16 * 8);
      float4 a = hp[0], b = hp[1];
      float h[8] = {a.x, a.y, a.z, a.w, b.x, b.y, b.z, b.w};
      #pragma unroll
      for (int i = 0; i < 8; i++) h[i] += 0.2f * nw[i];
      ((uint4*)ahi)[(size_t)node * 16 + l16] = pack8(h);
    }
  }
}

// ---------------- fused final GEMM via MFMA bf16 ------------------------------
// out = lrelu([ein | ahi | x] @ Wall + lin_b) + x0
// 512 threads / 128 rows / 8 waves per block; frag-ordered B, dbuf LDS,
// one barrier per chunk. NEW: STREAMED EPILOGUE — chunk ch fully computes
// col-tiles 2ch,2ch+1, so their x0 loads are issued before the chunk's MFMAs
// (latency hidden under compute) and bias/lrelu/store happen right after,
// overlapping the next chunk's staging. Kills the serial 100MB epilogue tail
// that ran after the last barrier with nothing to hide under.
__global__ __launch_bounds__(512)
void k_gemm2(const float* __restrict__ ein, const unsigned short* __restrict__ ahi,
             const float* __restrict__ x, const unsigned short* __restrict__ wfr,
             const float* __restrict__ lin_b, const float* __restrict__ x0,
             float* __restrict__ out) {
  __shared__ __align__(16) unsigned short Bs[2][24 * 512];
  int tid = threadIdx.x;
  int lane = tid & 63, wv = tid >> 6;          // 8 waves
  int quad = lane >> 4, l16 = lane & 15;
  int n0 = blockIdx.x * 128;
  int rA = n0 + wv * 16 + l16;
  if (rA >= N_NODES) rA = N_NODES - 1;      // clamped dup; store-guarded
  int kq = quad * 8;
  int gnb = n0 + wv * 16 + quad * 4;        // output row base for this thread

  // ---- preload lin_b for my 8 cols ----
  float blv[8];
  #pragma unroll
  for (int ct = 0; ct < 8; ct++) blv[ct] = lin_b[ct * 16 + l16];

  // ---- 12 a_frags in registers (A row = rA) ----
  short8 af[12];
  #pragma unroll
  for (int kb = 0; kb < 4; kb++) {          // cols 0-127: ein (fp32 -> bf16)
    const float4* p = (const float4*)(ein + (size_t)rA * 128 + kb * 32 + kq);
    float4 a = p[0], b = p[1];
    short8 t;
    t[0] = (short)f2bf(a.x); t[1] = (short)f2bf(a.y);
    t[2] = (short)f2bf(a.z); t[3] = (short)f2bf(a.w);
    t[4] = (short)f2bf(b.x); t[5] = (short)f2bf(b.y);
    t[6] = (short)f2bf(b.z); t[7] = (short)f2bf(b.w);
    af[kb] = t;
  }
  #pragma unroll
  for (int kb = 0; kb < 4; kb++)            // cols 128-255: ahi (bf16)
    af[4 + kb] = *(const short8*)(ahi + (size_t)rA * 128 + kb * 32 + kq);
  #pragma unroll
  for (int kb = 0; kb < 4; kb++) {          // cols 256-383: x (fp32 -> bf16)
    const float4* p = (const float4*)(x + (size_t)rA * 128 + kb * 32 + kq);
    float4 a = p[0], b = p[1];
    short8 t;
    t[0] = (short)f2bf(a.x); t[1] = (short)f2bf(a.y);
    t[2] = (short)f2bf(a.z); t[3] = (short)f2bf(a.w);
    t[4] = (short)f2bf(b.x); t[5] = (short)f2bf(b.y);
    t[6] = (short)f2bf(b.z); t[7] = (short)f2bf(b.w);
    af[8 + kb] = t;
  }

  f32x4 acc[8];
  #pragma unroll
  for (int i = 0; i < 8; i++) acc[i] = (f32x4){0.f, 0.f, 0.f, 0.f};

  const uint4* W4 = (const uint4*)wfr;      // 6144 uint4 total, 1536/chunk

  // ---- prologue: stage chunk 0 (512 threads x 3 uint4) ----
  {
    uint4 tmp[3];
    #pragma unroll
    for (int i = 0; i < 3; i++) tmp[i] = W4[tid + i * 512];
    uint4* B4 = (uint4*)Bs[0];
    #pragma unroll
    for (int i = 0; i < 3; i++) B4[tid + i * 512] = tmp[i];
  }
  __syncthreads();

  #pragma unroll
  for (int ch = 0; ch < 4; ch++) {
    int cur = ch & 1;
    // issue next chunk's global loads (in flight across the MFMAs below)
    uint4 tmp[3];
    if (ch < 3) {
      #pragma unroll
      for (int i = 0; i < 3; i++) tmp[i] = W4[(ch + 1) * 1536 + tid + i * 512];
    }
    // issue this chunk's x0 loads (consumed after the MFMAs)
    float x0v[8];
    #pragma unroll
    for (int ctl = 0; ctl < 2; ctl++) {
      int col = (ch * 2 + ctl) * 16 + l16;
      #pragma unroll
      for (int r = 0; r < 4; r++) {
        int gn = gnb + r;
        x0v[ctl * 4 + r] = (gn < N_NODES) ? x0[(size_t)gn * 128 + col] : 0.f;
      }
    }
    // compute on current chunk: 2 col-tiles x 12 kb
    const unsigned short* Bc = Bs[cur];
    #pragma unroll
    for (int ctl = 0; ctl < 2; ctl++) {
      #pragma unroll
      for (int kb = 0; kb < 12; kb++) {
        short8 b = *(const short8*)(Bc + (ctl * 12 + kb) * 512 + (lane << 3));
        acc[ch * 2 + ctl] =
            __builtin_amdgcn_mfma_f32_16x16x32_bf16(af[kb], b, acc[ch * 2 + ctl], 0, 0, 0);
      }
    }
    // streamed epilogue for this chunk's 2 col-tiles (overlaps staging below)
    #pragma unroll
    for (int ctl = 0; ctl < 2; ctl++) {
      int ct = ch * 2 + ctl;
      int col = ct * 16 + l16;
      #pragma unroll
      for (int r = 0; r < 4; r++) {
        int gn = gnb + r;
        if (gn < N_NODES) {
          float v = acc[ct][r] + blv[ct];
          v = (v > 0.f) ? v : 0.01f * v;
          out[(size_t)gn * 128 + col] = v + x0v[ctl * 4 + r];
        }
      }
    }
    // write next chunk and publish with a single barrier
    if (ch < 3) {
      uint4* B4 = (uint4*)Bs[cur ^ 1];
      #pragma unroll
      for (int i = 0; i < 3; i++) B4[tid + i * 512] = tmp[i];
      __syncthreads();
    }
  }
}

extern "C" void kernel_launch(void* const* d_in, const int* in_sizes, int n_in,
                              void* d_out, int out_size, void* d_ws, size_t ws_size,
                              hipStream_t stream) {
  const int*   src     = (const int*)d_in[0];
  const int*   dst     = (const int*)d_in[1];
  const float* x0      = (const float*)d_in[2];
  const float* x       = (const float*)d_in[3];
  const float* ein     = (const float*)d_in[4];
  const float* alpha   = (const float*)d_in[7];
  const float* emb     = (const float*)d_in[8];
  const float* w1      = (const float*)d_in[9];
  const float* b1      = (const float*)d_in[10];
  const float* w2      = (const float*)d_in[11];
  const float* b2      = (const float*)d_in[12];
  const float* weights = (const float*)d_in[13];
  const float* lin_w   = (const float*)d_in[14];
  const float* lin_b   = (const float*)d_in[15];
  float* out = (float*)d_out;

  // workspace layout (~82 MB)
  unsigned short* xk_bf  = (unsigned short*)d_ws;             // N*128 bf16
  unsigned short* xk1_bf = xk_bf  + (size_t)N_NODES * 128;
  unsigned short* ahi    = xk1_bf + (size_t)N_NODES * 128;
  unsigned short* wfr    = ahi    + (size_t)N_NODES * 128;    // 96*512 bf16 frag-order
  float* dinv = (float*)(wfr + 128 * 392);
  int* degs   = (int*)(dinv + N_NODES);
  int* offs   = degs + N_NODES;
  int* cursor = offs + N_NODES;
  int* aux    = cursor + N_NODES;
  int* aux2   = aux + 512;
  int* csr    = aux2 + 512;

  hipMemsetAsync(degs, 0, sizeof(int) * 3 * (size_t)N_NODES, stream);

  int gN = (N_NODES + 255) / 256;   // 391
  int gE = (N_EDGES + 255) / 256;

  // fused: MLP + degree count + weight precompute (independent work, 1 dispatch)
  k_front<<<G_MLP + G_DEG + G_PRE, 256, 0, stream>>>(
      x, w1, w2, b1, b2, emb, alpha, xk_bf, dst, degs, weights, lin_w, wfr);

  k_scan1<<<gN, 256, 0, stream>>>(degs, offs, aux);
  k_scan2<<<1, 512, 0, stream>>>(aux, aux2, gN);
  k_scan3<<<gN, 256, 0, stream>>>(offs, aux2, degs, dinv);
  k_fill <<<gE, 256, 0, stream>>>(src, dst, offs, cursor, csr);

  float* hi = out;   // fp32 hi lives in d_out between pass1 and gemm
  k_gather<1><<<N_NODES / 4, 256, 0, stream>>>(xk_bf,  xk1_bf, hi, nullptr, csr, offs, degs, dinv);
  k_gather<2><<<N_NODES / 4, 256, 0, stream>>>(xk1_bf, nullptr, hi, ahi,    csr, offs, degs, dinv);

  k_gemm2<<<(N_NODES + 127) / 128, 512, 0, stream>>>(ein, ahi, x, wfr, lin_b, x0, out);
}